// Round 1
// baseline (337.269 us; speedup 1.0000x reference)
//
#include <hip/hip_runtime.h>
#include <cstdint>

#define B_    8
#define C_    128
#define HW    4096      // 64*64
#define O_    128
#define KDIM  1152      // C_*9

typedef short bf16x8 __attribute__((ext_vector_type(8)));
typedef float f32x4  __attribute__((ext_vector_type(4)));

__device__ __forceinline__ unsigned short f2bf(float f) {
  unsigned u = __float_as_uint(f);
  u += 0x7FFFu + ((u >> 16) & 1u);
  return (unsigned short)(u >> 16);
}

// ---------------- workspace layout (bytes) ----------------
// conv_out : 8*27*4096 f32            = 3,538,944
// Wbf      : 128*1152 bf16            =   294,912
// wre      : 1152*27 f32              =   124,416
// partials / valT (lifetimes disjoint): max(14,155,776 , 75,497,472)
#define WS_CONVOUT 0
#define WS_WBF     3538944
#define WS_WRE     3833856
#define WS_BIG     3958272   // partials (k_conv/k_reduce) then valT (k_sample/k_gemm)

// K0: weight fp32->bf16; rearrange conv weights to wre[i=c*9+t][och 0..26]
__global__ void k_prep(const float* __restrict__ weight,
                       const float* __restrict__ w_off, const float* __restrict__ w_msk,
                       unsigned short* __restrict__ Wbf, float* __restrict__ wre) {
  int gid = blockIdx.x * 256 + threadIdx.x;
  if (gid < O_ * KDIM) Wbf[gid] = f2bf(weight[gid]);
  if (gid < KDIM * 27) {
    int i = gid / 27, och = gid - i * 27;
    // w_off layout (18,128,3,3): flat = och*1152 + i ; same for w_msk
    wre[gid] = (och < 18) ? w_off[och * KDIM + i] : w_msk[(och - 18) * KDIM + i];
  }
}

// K1: 27-channel 3x3 conv, 4-way split over input channels -> partials
__global__ __launch_bounds__(128) void k_conv(const float* __restrict__ x,
                                              const float* __restrict__ b_off,
                                              const float* __restrict__ b_msk,
                                              const float* __restrict__ wre,
                                              float* __restrict__ part) {
  int bid = blockIdx.x;
  int q  = bid >> 8;         // c-quarter 0..3
  int b  = (bid >> 5) & 7;
  int pt = bid & 31;
  int p  = pt * 128 + threadIdx.x;
  int ho = p >> 6, wo = p & 63;

  float acc[27];
#pragma unroll
  for (int o = 0; o < 27; ++o)
    acc[o] = (q == 0) ? ((o < 18) ? b_off[o] : b_msk[o - 18]) : 0.f;

  const float* xb = x + (size_t)b * C_ * HW;
  int c0 = q * 32;
  for (int cc = 0; cc < 32; ++cc) {
    int c = c0 + cc;
    const float* xc = xb + (size_t)c * HW;
    const float* wr = wre + c * 9 * 27;   // uniform -> scalar loads
#pragma unroll
    for (int t = 0; t < 9; ++t) {
      int ky = t / 3, kx = t - (t / 3) * 3;
      int iy = ho + ky - 1, ix = wo + kx - 1;
      float xv = ((unsigned)iy < 64u && (unsigned)ix < 64u) ? xc[iy * 64 + ix] : 0.f;
#pragma unroll
      for (int o = 0; o < 27; ++o)
        acc[o] = fmaf(wr[t * 27 + o], xv, acc[o]);
    }
  }
  float* pb = part + (size_t)(q * 8 + b) * 27 * HW + p;
#pragma unroll
  for (int o = 0; o < 27; ++o) pb[(size_t)o * HW] = acc[o];
}

// K1b: reduce 4 partials, sigmoid on mask channels (18..26)
__global__ void k_reduce(const float* __restrict__ part, float* __restrict__ conv_out) {
  int j = blockIdx.x * 256 + threadIdx.x;   // < 884736 exactly
  float v = part[j] + part[884736 + j] + part[2 * 884736 + j] + part[3 * 884736 + j];
  int och = (j >> 12) % 27;
  if (och >= 18) v = 1.f / (1.f + __expf(-v));
  conv_out[j] = v;
}

// K2: bilinear sample * mask -> valT[b][p][i=c*9+k2] bf16 (K-contiguous rows),
// transposed through LDS so global writes are coalesced.
__global__ __launch_bounds__(256) void k_sample(const float* __restrict__ x,
                                                const float* __restrict__ conv_out,
                                                unsigned short* __restrict__ valT) {
  __shared__ __align__(16) int4   sA[144];
  __shared__ __align__(16) float4 sW[144];
  __shared__ __align__(16) unsigned short vbuf[16 * 1156];  // padded row stride

  int bid = blockIdx.x;
  int b = bid >> 8;
  int pbase = (bid & 255) * 16;     // 16 pixels, same image row (16 | 64)
  int tid = threadIdx.x;

  if (tid < 144) {  // per (pixel, k2) bilinear params
    int pl = tid / 9, k2 = tid - pl * 9;
    int p = pbase + pl;
    int ho = p >> 6, wo = p & 63;
    int ky = k2 / 3, kx = k2 - ky * 3;
    const float* co = conv_out + (size_t)b * 27 * HW;
    float dy = co[(2 * k2) * HW + p];
    float dx = co[(2 * k2 + 1) * HW + p];
    float mk = co[(18 + k2) * HW + p];
    float py = dy + (float)(ho + ky - 1);
    float px = dx + (float)(wo + kx - 1);
    float fy = floorf(py), fx = floorf(px);
    float ly = py - fy, lx = px - fx;
    int y0 = (int)fy, x0 = (int)fx;
    float vy0 = ((unsigned)y0 < 64u) ? 1.f : 0.f;
    float vy1 = ((unsigned)(y0 + 1) < 64u) ? 1.f : 0.f;
    float vx0 = ((unsigned)x0 < 64u) ? 1.f : 0.f;
    float vx1 = ((unsigned)(x0 + 1) < 64u) ? 1.f : 0.f;
    int cy0 = min(max(y0, 0), 63), cy1 = min(max(y0 + 1, 0), 63);
    int cx0 = min(max(x0, 0), 63), cx1 = min(max(x0 + 1, 0), 63);
    float wy0 = (1.f - ly) * mk, wy1 = ly * mk;
    sW[tid] = make_float4(wy0 * (1.f - lx) * vy0 * vx0, wy0 * lx * vy0 * vx1,
                          wy1 * (1.f - lx) * vy1 * vx0, wy1 * lx * vy1 * vx1);
    sA[tid] = make_int4(cy0 * 64 + cx0, cy0 * 64 + cx1, cy1 * 64 + cx0, cy1 * 64 + cx1);
  }
  __syncthreads();

  int pl = tid & 15, cg = tid >> 4;   // 16 lanes share a channel -> coalesced-ish gathers
  int4 A[9]; float4 W[9];
#pragma unroll
  for (int k2 = 0; k2 < 9; ++k2) { A[k2] = sA[pl * 9 + k2]; W[k2] = sW[pl * 9 + k2]; }

  const float* xb = x + (size_t)b * C_ * HW;
  unsigned short* vrow = vbuf + pl * 1156;
#pragma unroll 1
  for (int cc = 0; cc < 8; ++cc) {
    int c = cg + (cc << 4);
    const float* xc = xb + (size_t)c * HW;
#pragma unroll
    for (int k2 = 0; k2 < 9; ++k2) {
      float v = W[k2].x * xc[A[k2].x] + W[k2].y * xc[A[k2].y]
              + W[k2].z * xc[A[k2].z] + W[k2].w * xc[A[k2].w];
      vrow[c * 9 + k2] = f2bf(v);
    }
  }
  __syncthreads();

  // coalesced write-out: 16 rows x 576 dwords
  int prow = tid >> 4, dcol = tid & 15;
  const unsigned* srow = (const unsigned*)(vbuf + prow * 1156);
  unsigned* dst = (unsigned*)(valT + ((size_t)b * HW + pbase + prow) * KDIM);
#pragma unroll
  for (int j = 0; j < 36; ++j) {
    int d = dcol + (j << 4);
    dst[d] = srow[d];
  }
}

// K3: out[b][o][p] = sum_i Wbf[o][i] * valT[b][p][i]  (both K-contiguous)
// 128x128 tile, 4 waves, BK=64, global_load_lds + XOR-swizzled LDS.
__global__ __launch_bounds__(256) void k_gemm(const unsigned short* __restrict__ Wbf,
                                              const unsigned short* __restrict__ valT,
                                              float* __restrict__ out) {
  __shared__ __align__(16) unsigned short Ash[128 * 64];
  __shared__ __align__(16) unsigned short Bsh[128 * 64];

  int bid = blockIdx.x;
  int b = bid >> 5;
  int pbase = (bid & 31) << 7;
  int tid = threadIdx.x;
  int lane = tid & 63, wv = tid >> 6;
  int wr = wv >> 1, wc = wv & 1;
  int lhi = lane >> 4, llo = lane & 15;

  const unsigned short* vb = valT + (size_t)(b * HW + pbase) * KDIM;

  int srow = tid >> 3;     // 0..31 (row within 32-row staging issue)
  int schunk = tid & 7;    // 16B chunk within BK=64 row segment

  f32x4 acc[4][4] = {};

  for (int kt = 0; kt < 18; ++kt) {
#pragma unroll
    for (int q = 0; q < 4; ++q) {
      int row = q * 32 + srow;
      int sch = schunk ^ (row & 7);   // inverse-swizzled SOURCE, linear LDS dest
      __builtin_amdgcn_global_load_lds(
          (const __attribute__((address_space(1))) unsigned int*)(Wbf + (size_t)row * KDIM + kt * 64 + sch * 8),
          (__attribute__((address_space(3))) unsigned int*)((char*)Ash + q * 4096 + wv * 1024),
          16, 0, 0);
      __builtin_amdgcn_global_load_lds(
          (const __attribute__((address_space(1))) unsigned int*)(vb + (size_t)row * KDIM + kt * 64 + sch * 8),
          (__attribute__((address_space(3))) unsigned int*)((char*)Bsh + q * 4096 + wv * 1024),
          16, 0, 0);
    }
    __syncthreads();

#pragma unroll
    for (int ks = 0; ks < 2; ++ks) {
      bf16x8 af[4], bfr[4];
#pragma unroll
      for (int m = 0; m < 4; ++m) {
        int row = wr * 64 + m * 16 + llo;
        int off = row * 128 + ((ks * 64 + lhi * 16) ^ ((llo & 7) << 4));  // swizzled read
        af[m] = *(const bf16x8*)((const char*)Ash + off);
      }
#pragma unroll
      for (int n = 0; n < 4; ++n) {
        int row = wc * 64 + n * 16 + llo;
        int off = row * 128 + ((ks * 64 + lhi * 16) ^ ((llo & 7) << 4));
        bfr[n] = *(const bf16x8*)((const char*)Bsh + off);
      }
#pragma unroll
      for (int m = 0; m < 4; ++m)
#pragma unroll
        for (int n = 0; n < 4; ++n)
          acc[m][n] = __builtin_amdgcn_mfma_f32_16x16x32_bf16(af[m], bfr[n], acc[m][n], 0, 0, 0);
    }
    __syncthreads();
  }

  // epilogue: C/D layout col=lane&15 (pixel), row=(lane>>4)*4+reg (o)
  float* ob = out + (size_t)b * O_ * HW + pbase;
#pragma unroll
  for (int m = 0; m < 4; ++m) {
    int o0 = wr * 64 + m * 16 + lhi * 4;
#pragma unroll
    for (int n = 0; n < 4; ++n) {
      int pl = wc * 64 + n * 16 + llo;
#pragma unroll
      for (int r = 0; r < 4; ++r)
        ob[(size_t)(o0 + r) * HW + pl] = acc[m][n][r];
    }
  }
}

extern "C" void kernel_launch(void* const* d_in, const int* in_sizes, int n_in,
                              void* d_out, int out_size, void* d_ws, size_t ws_size,
                              hipStream_t stream) {
  const float* x      = (const float*)d_in[0];
  const float* w_off  = (const float*)d_in[1];
  const float* b_off  = (const float*)d_in[2];
  const float* w_msk  = (const float*)d_in[3];
  const float* b_msk  = (const float*)d_in[4];
  const float* weight = (const float*)d_in[5];
  float* out = (float*)d_out;
  char* ws = (char*)d_ws;

  float*          conv_out = (float*)(ws + WS_CONVOUT);
  unsigned short* Wbf      = (unsigned short*)(ws + WS_WBF);
  float*          wre      = (float*)(ws + WS_WRE);
  float*          part     = (float*)(ws + WS_BIG);           // k_conv lifetime
  unsigned short* valT     = (unsigned short*)(ws + WS_BIG);  // k_sample lifetime

  k_prep  <<<576, 256, 0, stream>>>(weight, w_off, w_msk, Wbf, wre);
  k_conv  <<<1024, 128, 0, stream>>>(x, b_off, b_msk, wre, part);
  k_reduce<<<3456, 256, 0, stream>>>(part, conv_out);
  k_sample<<<2048, 256, 0, stream>>>(x, conv_out, valT);
  k_gemm  <<<256, 256, 0, stream>>>(Wbf, valT, out);
}

// Round 4
// 203.058 us; speedup vs baseline: 1.6610x; 1.6610x over previous
//
#include <hip/hip_runtime.h>
#include <cstdint>

#define B_    8
#define C_    128
#define HW    4096      // 64*64
#define O_    128
#define KDIM  1152      // C_*9

typedef short bf16x8 __attribute__((ext_vector_type(8)));
typedef float f32x4  __attribute__((ext_vector_type(4)));

__device__ __forceinline__ unsigned short f2bf(float f) {
  unsigned u = __float_as_uint(f);
  u += 0x7FFFu + ((u >> 16) & 1u);
  return (unsigned short)(u >> 16);
}
__device__ __forceinline__ float bf_lo(unsigned u) { return __uint_as_float(u << 16); }
__device__ __forceinline__ float bf_hi(unsigned u) { return __uint_as_float(u & 0xFFFF0000u); }

// ---------------- workspace layout (bytes) ----------------
#define WS_CONVOUT 0          // 8*27*4096*4            = 3,538,944
#define WS_WBF     3538944    // 128*1152*2             =   294,912
#define WS_WRE     3833856    // 1152*27*4              =   124,416
#define WS_XT      3958272    // 8*4096*128*2           = 8,388,608
#define WS_BIG     12346880   // part 8*8*27*4096*4 = 28.3MB (k_conv->k_reduce)
                              // then valT 8*4096*1152*2 = 75.5MB (k_sample->k_gemm)
                              // total ws end = 87,844,352

// K0: Wbf[o][k2*128+c] = weight[o][c][k2] (bf16); wre[i=c*9+t][och 0..26]
__global__ void k_prep(const float* __restrict__ weight,
                       const float* __restrict__ w_off, const float* __restrict__ w_msk,
                       unsigned short* __restrict__ Wbf, float* __restrict__ wre) {
  int gid = blockIdx.x * 256 + threadIdx.x;
  if (gid < O_ * KDIM) {
    int o = gid / KDIM, i = gid - o * KDIM;
    int k2 = i >> 7, c = i & 127;
    Wbf[gid] = f2bf(weight[o * KDIM + c * 9 + k2]);
  }
  if (gid < KDIM * 27) {
    int i = gid / 27, och = gid - i * 27;
    wre[gid] = (och < 18) ? w_off[och * KDIM + i] : w_msk[(och - 18) * KDIM + i];
  }
}

// K0b: transpose x[b][c][p] f32 -> xt[b][p][c] bf16 (pixel-major rows of 128 ch)
__global__ __launch_bounds__(256) void k_xt(const float* __restrict__ x,
                                            unsigned short* __restrict__ xt) {
  __shared__ unsigned short tile[64][130];   // +2 u16 pad: stride 65 dwords -> conflict-free
  int bid = blockIdx.x;                      // 8 b * 64 ptiles
  int b = bid >> 6, p0 = (bid & 63) << 6;
  int tid = threadIdx.x;
  int pl = tid & 63, cq = tid >> 6;          // wave-coalesced along p
  const float* xb = x + (size_t)b * C_ * HW + p0 + pl;
#pragma unroll
  for (int i = 0; i < 32; ++i) {
    int c = cq * 32 + i;
    tile[pl][c] = f2bf(xb[(size_t)c * HW]);
  }
  __syncthreads();
  int cd = tid & 63, pr = tid >> 6;
  unsigned* dst = (unsigned*)xt + ((size_t)b * HW + p0) * 64 + cd;
  const unsigned* t32 = (const unsigned*)&tile[0][0];
#pragma unroll
  for (int j = 0; j < 16; ++j) {
    int p = pr + j * 4;
    dst[(size_t)p * 64] = t32[p * 65 + cd];
  }
}

// K1: 27-channel 3x3 conv, 8-way channel split -> partials
__global__ __launch_bounds__(128, 4) void k_conv(const float* __restrict__ x,
                                                 const float* __restrict__ b_off,
                                                 const float* __restrict__ b_msk,
                                                 const float* __restrict__ wre,
                                                 float* __restrict__ part) {
  int bid = blockIdx.x;        // 8q * 8b * 32pt = 2048
  int q  = bid >> 8;           // 0..7 (16 channels each)
  int b  = (bid >> 5) & 7;
  int pt = bid & 31;
  int p  = pt * 128 + threadIdx.x;
  int ho = p >> 6, wo = p & 63;

  // hoisted tap offsets + validity (per-thread constant over channels)
  int xoff[9]; float vm[9];
#pragma unroll
  for (int t = 0; t < 9; ++t) {
    int ky = t / 3, kx = t - (t / 3) * 3;
    int iy = ho + ky - 1, ix = wo + kx - 1;
    bool v = ((unsigned)iy < 64u) && ((unsigned)ix < 64u);
    xoff[t] = v ? iy * 64 + ix : 0;
    vm[t] = v ? 1.f : 0.f;
  }

  float acc[27];
#pragma unroll
  for (int o = 0; o < 27; ++o)
    acc[o] = (q == 0) ? ((o < 18) ? b_off[o] : b_msk[o - 18]) : 0.f;

  const float* xc = x + (size_t)(b * C_ + q * 16) * HW;
  const float* wr = wre + (size_t)(q * 16) * 243;   // 9*27 per channel, scalar loads

  float xv[9], xn[9];
#pragma unroll
  for (int t = 0; t < 9; ++t) xv[t] = xc[xoff[t]] * vm[t];

  for (int cc = 0; cc < 16; ++cc) {
    if (cc < 15) {                       // prefetch next channel during FMAs
      const float* xp = xc + (size_t)(cc + 1) * HW;
#pragma unroll
      for (int t = 0; t < 9; ++t) xn[t] = xp[xoff[t]] * vm[t];
    }
#pragma unroll
    for (int t = 0; t < 9; ++t)
#pragma unroll
      for (int o = 0; o < 27; ++o)
        acc[o] = fmaf(wr[cc * 243 + t * 27 + o], xv[t], acc[o]);
#pragma unroll
    for (int t = 0; t < 9; ++t) xv[t] = xn[t];
  }

  float* pb = part + (size_t)(q * 8 + b) * 27 * HW + p;
#pragma unroll
  for (int o = 0; o < 27; ++o) pb[(size_t)o * HW] = acc[o];
}

// K1b: reduce 8 partials, sigmoid on mask channels
__global__ void k_reduce(const float* __restrict__ part, float* __restrict__ conv_out) {
  int j = blockIdx.x * 256 + threadIdx.x;   // < 884736 exactly
  float v = 0.f;
#pragma unroll
  for (int s = 0; s < 8; ++s) v += part[(size_t)s * 884736 + j];
  int och = (j >> 12) % 27;
  if (och >= 18) v = 1.f / (1.f + __expf(-v));
  conv_out[j] = v;
}

// K2: one wave per (b,p,k2): 4 coalesced 256B row loads from xt, bilinear,
// coalesced 256B store to valT[b][p][k2*128+c]
__global__ __launch_bounds__(256) void k_sample(const unsigned* __restrict__ xt32,
                                                const float* __restrict__ conv_out,
                                                unsigned* __restrict__ valT32) {
  int tid = threadIdx.x, lane = tid & 63, wv = tid >> 6;
  int task = blockIdx.x * 4 + wv;          // < 294912 = 8*4096*9
  int k2 = task % 9;
  int bp = task / 9;
  int b = bp >> 12, p = bp & 4095;
  int ho = p >> 6, wo = p & 63;
  int ky = k2 / 3, kx = k2 - ky * 3;

  const float* co = conv_out + (size_t)b * 27 * HW + p;
  float dy = co[(size_t)(2 * k2) * HW];
  float dx = co[(size_t)(2 * k2 + 1) * HW];
  float mk = co[(size_t)(18 + k2) * HW];

  float py = dy + (float)(ho + ky - 1);
  float px = dx + (float)(wo + kx - 1);
  float fy = floorf(py), fx = floorf(px);
  float ly = py - fy, lx = px - fx;
  int y0 = (int)fy, x0 = (int)fx;
  float vy0 = ((unsigned)y0 < 64u) ? 1.f : 0.f;
  float vy1 = ((unsigned)(y0 + 1) < 64u) ? 1.f : 0.f;
  float vx0 = ((unsigned)x0 < 64u) ? 1.f : 0.f;
  float vx1 = ((unsigned)(x0 + 1) < 64u) ? 1.f : 0.f;
  int cy0 = min(max(y0, 0), 63), cy1 = min(max(y0 + 1, 0), 63);
  int cx0 = min(max(x0, 0), 63), cx1 = min(max(x0 + 1, 0), 63);
  float wy0 = (1.f - ly) * mk, wy1 = ly * mk;
  float w00 = wy0 * (1.f - lx) * vy0 * vx0, w01 = wy0 * lx * vy0 * vx1;
  float w10 = wy1 * (1.f - lx) * vy1 * vx0, w11 = wy1 * lx * vy1 * vx1;

  const unsigned* xb = xt32 + ((size_t)b * HW << 6);
  unsigned v00 = xb[(size_t)(cy0 * 64 + cx0) * 64 + lane];
  unsigned v01 = xb[(size_t)(cy0 * 64 + cx1) * 64 + lane];
  unsigned v10 = xb[(size_t)(cy1 * 64 + cx0) * 64 + lane];
  unsigned v11 = xb[(size_t)(cy1 * 64 + cx1) * 64 + lane];

  float lo = w00 * bf_lo(v00) + w01 * bf_lo(v01) + w10 * bf_lo(v10) + w11 * bf_lo(v11);
  float hi = w00 * bf_hi(v00) + w01 * bf_hi(v01) + w10 * bf_hi(v10) + w11 * bf_hi(v11);
  unsigned pk = (unsigned)f2bf(lo) | ((unsigned)f2bf(hi) << 16);
  valT32[(size_t)bp * 576 + k2 * 64 + lane] = pk;
}

// K3: out[b][o][p] = sum_i Wbf[o][i] * valT[b][p][i]
// tile 128(M=O) x 64(N=pixels), BK=64, 512 blocks (2/CU), double-buffered
__global__ __launch_bounds__(256, 2) void k_gemm(const unsigned short* __restrict__ Wbf,
                                                 const unsigned short* __restrict__ valT,
                                                 float* __restrict__ out) {
  __shared__ __align__(16) unsigned short As[2][128 * 64];  // 16KB each
  __shared__ __align__(16) unsigned short Bs[2][64 * 64];   //  8KB each

  int bid = blockIdx.x;            // 512 = 8b * 64 ptiles
  int b = bid >> 6;
  int pbase = (bid & 63) << 6;
  int tid = threadIdx.x, lane = tid & 63, wv = tid >> 6;
  int lhi = lane >> 4, llo = lane & 15;

  const unsigned short* vb = valT + ((size_t)b * HW + pbase) * KDIM;

  f32x4 acc[2][4] = {};

  auto STAGE = [&](int kt, int bufi) {
#pragma unroll
    for (int j = 0; j < 4; ++j) {            // A: 128 rows x 128B = 1024 chunks
      int chunk = j * 256 + tid;
      int row = chunk >> 3;
      int sch = (chunk & 7) ^ (row & 7);     // inverse-swizzled source, linear dest
      __builtin_amdgcn_global_load_lds(
          (const __attribute__((address_space(1))) unsigned*)(Wbf + (size_t)row * KDIM + kt * 64 + sch * 8),
          (__attribute__((address_space(3))) unsigned*)((char*)&As[bufi][0] + j * 4096 + wv * 1024),
          16, 0, 0);
    }
#pragma unroll
    for (int j = 0; j < 2; ++j) {            // B: 64 rows x 128B = 512 chunks
      int chunk = j * 256 + tid;
      int row = chunk >> 3;
      int sch = (chunk & 7) ^ (row & 7);
      __builtin_amdgcn_global_load_lds(
          (const __attribute__((address_space(1))) unsigned*)(vb + (size_t)row * KDIM + kt * 64 + sch * 8),
          (__attribute__((address_space(3))) unsigned*)((char*)&Bs[bufi][0] + j * 4096 + wv * 1024),
          16, 0, 0);
    }
  };

  STAGE(0, 0);
  __syncthreads();

  int buf = 0;
  for (int kt = 0; kt < 18; ++kt) {
    if (kt < 17) STAGE(kt + 1, buf ^ 1);     // async prefetch overlaps compute
#pragma unroll
    for (int ks = 0; ks < 2; ++ks) {
      bf16x8 af[2], bfv[4];
#pragma unroll
      for (int m = 0; m < 2; ++m) {
        int row = wv * 32 + m * 16 + llo;
        int off = row * 128 + ((ks * 64 + lhi * 16) ^ ((llo & 7) << 4));
        af[m] = *(const bf16x8*)((const char*)&As[buf][0] + off);
      }
#pragma unroll
      for (int n = 0; n < 4; ++n) {
        int row = n * 16 + llo;
        int off = row * 128 + ((ks * 64 + lhi * 16) ^ ((llo & 7) << 4));
        bfv[n] = *(const bf16x8*)((const char*)&Bs[buf][0] + off);
      }
#pragma unroll
      for (int m = 0; m < 2; ++m)
#pragma unroll
        for (int n = 0; n < 4; ++n)
          acc[m][n] = __builtin_amdgcn_mfma_f32_16x16x32_bf16(af[m], bfv[n], acc[m][n], 0, 0, 0);
    }
    __syncthreads();                         // drains vmcnt -> next buf staged
    buf ^= 1;
  }

  float* ob = out + (size_t)b * O_ * HW + pbase;
#pragma unroll
  for (int m = 0; m < 2; ++m) {
    int o0 = wv * 32 + m * 16 + lhi * 4;
#pragma unroll
    for (int n = 0; n < 4; ++n) {
      int pl = n * 16 + llo;
#pragma unroll
      for (int r = 0; r < 4; ++r)
        ob[(size_t)(o0 + r) * HW + pl] = acc[m][n][r];
    }
  }
}

extern "C" void kernel_launch(void* const* d_in, const int* in_sizes, int n_in,
                              void* d_out, int out_size, void* d_ws, size_t ws_size,
                              hipStream_t stream) {
  const float* x      = (const float*)d_in[0];
  const float* w_off  = (const float*)d_in[1];
  const float* b_off  = (const float*)d_in[2];
  const float* w_msk  = (const float*)d_in[3];
  const float* b_msk  = (const float*)d_in[4];
  const float* weight = (const float*)d_in[5];
  float* out = (float*)d_out;
  char* ws = (char*)d_ws;

  float*          conv_out = (float*)(ws + WS_CONVOUT);
  unsigned short* Wbf      = (unsigned short*)(ws + WS_WBF);
  float*          wre      = (float*)(ws + WS_WRE);
  unsigned short* xt       = (unsigned short*)(ws + WS_XT);
  float*          part     = (float*)(ws + WS_BIG);           // k_conv lifetime
  unsigned short* valT     = (unsigned short*)(ws + WS_BIG);  // k_sample lifetime

  k_prep  <<<576, 256, 0, stream>>>(weight, w_off, w_msk, Wbf, wre);
  k_xt    <<<512, 256, 0, stream>>>(x, xt);
  k_conv  <<<2048, 128, 0, stream>>>(x, b_off, b_msk, wre, part);
  k_reduce<<<3456, 256, 0, stream>>>(part, conv_out);
  k_sample<<<73728, 256, 0, stream>>>((const unsigned*)xt, conv_out, (unsigned*)valT);
  k_gemm  <<<512, 256, 0, stream>>>(Wbf, valT, out);
}

// Round 5
// 190.571 us; speedup vs baseline: 1.7698x; 1.0655x over previous
//
#include <hip/hip_runtime.h>
#include <hip/hip_fp16.h>
#include <cstdint>

#define B_    8
#define C_    128
#define HW    4096      // 64*64
#define O_    128
#define KDIM  1152      // C_*9

typedef short bf16x8 __attribute__((ext_vector_type(8)));
typedef float f32x4  __attribute__((ext_vector_type(4)));

__device__ __forceinline__ unsigned short f2bf(float f) {
  unsigned u = __float_as_uint(f);
  u += 0x7FFFu + ((u >> 16) & 1u);
  return (unsigned short)(u >> 16);
}
__device__ __forceinline__ float bf_lo(unsigned u) { return __uint_as_float(u << 16); }
__device__ __forceinline__ float bf_hi(unsigned u) { return __uint_as_float(u & 0xFFFF0000u); }

// ---------------- workspace layout (bytes) ----------------
#define WS_WBF 0          // 128*1152*2            =   294,912
#define WS_WRE 294912     // 1152*27*4             =   124,416
#define WS_XT  419328     // 8*4096*128*2          = 8,388,608
#define WS_PW  8807936    // 294912*8 (f16x4)      = 2,359,296
#define WS_PA  11167232   // 294912*4 (u32)        = 1,179,648
#define WS_BIG 12346880   // part 8*8*27*4096*4 = 28.3MB (k_conv->k_rp)
                          // then valT 8*4096*1152*2 = 75.5MB (k_sample->k_gemm)
                          // end = 87,844,352 (same as known-good r1 layout)

// K0: Wbf[o][k2*128+c] = weight[o][c][k2] (bf16); wre[i=c*9+t][och 0..26]
__global__ void k_prep(const float* __restrict__ weight,
                       const float* __restrict__ w_off, const float* __restrict__ w_msk,
                       unsigned short* __restrict__ Wbf, float* __restrict__ wre) {
  int gid = blockIdx.x * 256 + threadIdx.x;
  if (gid < O_ * KDIM) {
    int o = gid / KDIM, i = gid - o * KDIM;
    int k2 = i >> 7, c = i & 127;
    Wbf[gid] = f2bf(weight[o * KDIM + c * 9 + k2]);
  }
  if (gid < KDIM * 27) {
    int i = gid / 27, och = gid - i * 27;
    wre[gid] = (och < 18) ? w_off[och * KDIM + i] : w_msk[(och - 18) * KDIM + i];
  }
}

// K0b: transpose x[b][c][p] f32 -> xt[b][p][c] bf16
__global__ __launch_bounds__(256) void k_xt(const float* __restrict__ x,
                                            unsigned short* __restrict__ xt) {
  __shared__ unsigned short tile[64][130];   // stride 65 dwords -> conflict-free
  int bid = blockIdx.x;                      // 8 b * 64 ptiles
  int b = bid >> 6, p0 = (bid & 63) << 6;
  int tid = threadIdx.x;
  int pl = tid & 63, cq = tid >> 6;
  const float* xb = x + (size_t)b * C_ * HW + p0 + pl;
#pragma unroll
  for (int i = 0; i < 32; ++i) {
    int c = cq * 32 + i;
    tile[pl][c] = f2bf(xb[(size_t)c * HW]);
  }
  __syncthreads();
  int cd = tid & 63, pr = tid >> 6;
  unsigned* dst = (unsigned*)xt + ((size_t)b * HW + p0) * 64 + cd;
  const unsigned* t32 = (const unsigned*)&tile[0][0];
#pragma unroll
  for (int j = 0; j < 16; ++j) {
    int p = pr + j * 4;
    dst[(size_t)p * 64] = t32[p * 65 + cd];
  }
}

// K1: 27-channel 3x3 conv, 8-way channel split -> partials
__global__ __launch_bounds__(128, 4) void k_conv(const float* __restrict__ x,
                                                 const float* __restrict__ b_off,
                                                 const float* __restrict__ b_msk,
                                                 const float* __restrict__ wre,
                                                 float* __restrict__ part) {
  int bid = blockIdx.x;        // 8q * 8b * 32pt = 2048
  int q  = bid >> 8;
  int b  = (bid >> 5) & 7;
  int pt = bid & 31;
  int p  = pt * 128 + threadIdx.x;
  int ho = p >> 6, wo = p & 63;

  int xoff[9]; float vm[9];
#pragma unroll
  for (int t = 0; t < 9; ++t) {
    int ky = t / 3, kx = t - (t / 3) * 3;
    int iy = ho + ky - 1, ix = wo + kx - 1;
    bool v = ((unsigned)iy < 64u) && ((unsigned)ix < 64u);
    xoff[t] = v ? iy * 64 + ix : 0;
    vm[t] = v ? 1.f : 0.f;
  }

  float acc[27];
#pragma unroll
  for (int o = 0; o < 27; ++o)
    acc[o] = (q == 0) ? ((o < 18) ? b_off[o] : b_msk[o - 18]) : 0.f;

  const float* xc = x + (size_t)(b * C_ + q * 16) * HW;
  const float* wr = wre + (size_t)(q * 16) * 243;

  float xv[9], xn[9];
#pragma unroll
  for (int t = 0; t < 9; ++t) xv[t] = xc[xoff[t]] * vm[t];

  for (int cc = 0; cc < 16; ++cc) {
    if (cc < 15) {
      const float* xp = xc + (size_t)(cc + 1) * HW;
#pragma unroll
      for (int t = 0; t < 9; ++t) xn[t] = xp[xoff[t]] * vm[t];
    }
#pragma unroll
    for (int t = 0; t < 9; ++t)
#pragma unroll
      for (int o = 0; o < 27; ++o)
        acc[o] = fmaf(wr[cc * 243 + t * 27 + o], xv[t], acc[o]);
#pragma unroll
    for (int t = 0; t < 9; ++t) xv[t] = xn[t];
  }

  float* pb = part + (size_t)(q * 8 + b) * 27 * HW + p;
#pragma unroll
  for (int o = 0; o < 27; ++o) pb[(size_t)o * HW] = acc[o];
}

// K1b: reduce partials + sigmoid + bilinear-param precompute (conv_out eliminated)
// gid = (b*9+k2)*HW + p ; emits pwh = 4 x f16 folded weights, paw = {row12|dxf|dyf}
__global__ __launch_bounds__(256) void k_rp(const float* __restrict__ part,
                                            uint2* __restrict__ pwh,
                                            unsigned* __restrict__ paw) {
  int gid = blockIdx.x * 256 + threadIdx.x;   // < 294912
  int p = gid & 4095;
  int bk = gid >> 12;          // b*9+k2 (block-uniform)
  int b = bk / 9, k2 = bk - b * 9;

  float dy = 0.f, dx = 0.f, mk = 0.f;
#pragma unroll
  for (int s = 0; s < 8; ++s) {
    const float* pb = part + ((size_t)(s * 8 + b) * 27) * HW + p;
    dy += pb[(size_t)(2 * k2) * HW];
    dx += pb[(size_t)(2 * k2 + 1) * HW];
    mk += pb[(size_t)(18 + k2) * HW];
  }
  mk = 1.f / (1.f + __expf(-mk));

  int ho = p >> 6, wo = p & 63;
  int ky = k2 / 3, kx = k2 - ky * 3;
  float py = dy + (float)(ho + ky - 1);
  float px = dx + (float)(wo + kx - 1);
  float fy = floorf(py), fx = floorf(px);
  float ly = py - fy, lx = px - fx;
  int y0 = (int)fy, x0 = (int)fx;
  float vy0 = ((unsigned)y0 < 64u) ? 1.f : 0.f;
  float vy1 = ((unsigned)(y0 + 1) < 64u) ? 1.f : 0.f;
  float vx0 = ((unsigned)x0 < 64u) ? 1.f : 0.f;
  float vx1 = ((unsigned)(x0 + 1) < 64u) ? 1.f : 0.f;
  int cy0 = min(max(y0, 0), 63);
  int cx0 = min(max(x0, 0), 63);
  float wy0 = (1.f - ly) * mk, wy1 = ly * mk;
  float w00 = wy0 * (1.f - lx) * vy0 * vx0, w01 = wy0 * lx * vy0 * vx1;
  float w10 = wy1 * (1.f - lx) * vy1 * vx0, w11 = wy1 * lx * vy1 * vx1;

  int dxf = (x0 >= 0 && x0 <= 62) ? 1 : 0;   // cx1 == cx0+1 ?
  int dyf = (y0 >= 0 && y0 <= 62) ? 1 : 0;   // cy1 == cy0+1 ?

  unsigned h00 = __half_as_ushort(__float2half_rn(w00));
  unsigned h01 = __half_as_ushort(__float2half_rn(w01));
  unsigned h10 = __half_as_ushort(__float2half_rn(w10));
  unsigned h11 = __half_as_ushort(__float2half_rn(w11));
  pwh[gid] = make_uint2(h00 | (h01 << 16), h10 | (h11 << 16));
  paw[gid] = (unsigned)(cy0 * 64 + cx0) | (dxf << 12) | (dyf << 13);
}

// K2: wave per (b,p,k2); params via scalar loads; 4 coalesced 256B gathers; blend; store
__global__ __launch_bounds__(256) void k_sample(const unsigned* __restrict__ xt32,
                                                const uint2* __restrict__ pwh,
                                                const unsigned* __restrict__ paw,
                                                unsigned* __restrict__ valT32) {
  int tid = threadIdx.x;
  int lane = tid & 63;
  int wuni = __builtin_amdgcn_readfirstlane(tid >> 6);
  int task = blockIdx.x * 4 + wuni;          // wave-uniform, < 294912
  int k2 = task % 9;
  int bp = task / 9;                          // b*4096+p
  int b = bp >> 12, p = bp & 4095;
  int pidx = (b * 9 + k2) * HW + p;           // params in (b,k2,p) order

  uint2 W = pwh[pidx];                        // scalar dwordx2
  unsigned aw = paw[pidx];                    // scalar dword
  __half2 h0 = *reinterpret_cast<__half2*>(&W.x);
  __half2 h1 = *reinterpret_cast<__half2*>(&W.y);
  float2 f0 = __half22float2(h0), f1 = __half22float2(h1);
  float w00 = f0.x, w01 = f0.y, w10 = f1.x, w11 = f1.y;

  unsigned a00 = (aw & 4095u) << 6;
  unsigned dxs = ((aw >> 12) & 1u) << 6;      // +1 col = +64 u32
  unsigned dys = ((aw >> 13) & 1u) << 12;     // +1 row = +4096 u32

  const unsigned* xb = xt32 + ((size_t)b << 18);
  unsigned v00 = xb[a00 + lane];
  unsigned v01 = xb[a00 + dxs + lane];
  unsigned v10 = xb[a00 + dys + lane];
  unsigned v11 = xb[a00 + dys + dxs + lane];

  float lo = w00 * bf_lo(v00) + w01 * bf_lo(v01) + w10 * bf_lo(v10) + w11 * bf_lo(v11);
  float hi = w00 * bf_hi(v00) + w01 * bf_hi(v01) + w10 * bf_hi(v10) + w11 * bf_hi(v11);
  unsigned pk = (unsigned)f2bf(lo) | ((unsigned)f2bf(hi) << 16);
  valT32[(size_t)bp * 576 + k2 * 64 + lane] = pk;
}

// K3: out[b][o][p] = sum_i Wbf[o][i] * valT[b][p][i]
__global__ __launch_bounds__(256, 2) void k_gemm(const unsigned short* __restrict__ Wbf,
                                                 const unsigned short* __restrict__ valT,
                                                 float* __restrict__ out) {
  __shared__ __align__(16) unsigned short As[2][128 * 64];
  __shared__ __align__(16) unsigned short Bs[2][64 * 64];

  int bid = blockIdx.x;            // 512 = 8b * 64 ptiles
  int b = bid >> 6;
  int pbase = (bid & 63) << 6;
  int tid = threadIdx.x, lane = tid & 63, wv = tid >> 6;
  int lhi = lane >> 4, llo = lane & 15;

  const unsigned short* vb = valT + ((size_t)b * HW + pbase) * KDIM;

  f32x4 acc[2][4] = {};

  auto STAGE = [&](int kt, int bufi) {
#pragma unroll
    for (int j = 0; j < 4; ++j) {
      int chunk = j * 256 + tid;
      int row = chunk >> 3;
      int sch = (chunk & 7) ^ (row & 7);
      __builtin_amdgcn_global_load_lds(
          (const __attribute__((address_space(1))) unsigned*)(Wbf + (size_t)row * KDIM + kt * 64 + sch * 8),
          (__attribute__((address_space(3))) unsigned*)((char*)&As[bufi][0] + j * 4096 + wv * 1024),
          16, 0, 0);
    }
#pragma unroll
    for (int j = 0; j < 2; ++j) {
      int chunk = j * 256 + tid;
      int row = chunk >> 3;
      int sch = (chunk & 7) ^ (row & 7);
      __builtin_amdgcn_global_load_lds(
          (const __attribute__((address_space(1))) unsigned*)(vb + (size_t)row * KDIM + kt * 64 + sch * 8),
          (__attribute__((address_space(3))) unsigned*)((char*)&Bs[bufi][0] + j * 4096 + wv * 1024),
          16, 0, 0);
    }
  };

  STAGE(0, 0);
  __syncthreads();

  int buf = 0;
  for (int kt = 0; kt < 18; ++kt) {
    if (kt < 17) STAGE(kt + 1, buf ^ 1);
#pragma unroll
    for (int ks = 0; ks < 2; ++ks) {
      bf16x8 af[2], bfv[4];
#pragma unroll
      for (int m = 0; m < 2; ++m) {
        int row = wv * 32 + m * 16 + llo;
        int off = row * 128 + ((ks * 64 + lhi * 16) ^ ((llo & 7) << 4));
        af[m] = *(const bf16x8*)((const char*)&As[buf][0] + off);
      }
#pragma unroll
      for (int n = 0; n < 4; ++n) {
        int row = n * 16 + llo;
        int off = row * 128 + ((ks * 64 + lhi * 16) ^ ((llo & 7) << 4));
        bfv[n] = *(const bf16x8*)((const char*)&Bs[buf][0] + off);
      }
#pragma unroll
      for (int m = 0; m < 2; ++m)
#pragma unroll
        for (int n = 0; n < 4; ++n)
          acc[m][n] = __builtin_amdgcn_mfma_f32_16x16x32_bf16(af[m], bfv[n], acc[m][n], 0, 0, 0);
    }
    __syncthreads();
    buf ^= 1;
  }

  float* ob = out + (size_t)b * O_ * HW + pbase;
#pragma unroll
  for (int m = 0; m < 2; ++m) {
    int o0 = wv * 32 + m * 16 + lhi * 4;
#pragma unroll
    for (int n = 0; n < 4; ++n) {
      int pl = n * 16 + llo;
#pragma unroll
      for (int r = 0; r < 4; ++r)
        ob[(size_t)(o0 + r) * HW + pl] = acc[m][n][r];
    }
  }
}

extern "C" void kernel_launch(void* const* d_in, const int* in_sizes, int n_in,
                              void* d_out, int out_size, void* d_ws, size_t ws_size,
                              hipStream_t stream) {
  const float* x      = (const float*)d_in[0];
  const float* w_off  = (const float*)d_in[1];
  const float* b_off  = (const float*)d_in[2];
  const float* w_msk  = (const float*)d_in[3];
  const float* b_msk  = (const float*)d_in[4];
  const float* weight = (const float*)d_in[5];
  float* out = (float*)d_out;
  char* ws = (char*)d_ws;

  unsigned short* Wbf  = (unsigned short*)(ws + WS_WBF);
  float*          wre  = (float*)(ws + WS_WRE);
  unsigned short* xt   = (unsigned short*)(ws + WS_XT);
  uint2*          pwh  = (uint2*)(ws + WS_PW);
  unsigned*       paw  = (unsigned*)(ws + WS_PA);
  float*          part = (float*)(ws + WS_BIG);           // k_conv -> k_rp
  unsigned short* valT = (unsigned short*)(ws + WS_BIG);  // k_sample -> k_gemm

  k_prep  <<<576, 256, 0, stream>>>(weight, w_off, w_msk, Wbf, wre);
  k_xt    <<<512, 256, 0, stream>>>(x, xt);
  k_conv  <<<2048, 128, 0, stream>>>(x, b_off, b_msk, wre, part);
  k_rp    <<<1152, 256, 0, stream>>>(part, pwh, paw);
  k_sample<<<73728, 256, 0, stream>>>((const unsigned*)xt, pwh, paw, (unsigned*)valT);
  k_gemm  <<<512, 256, 0, stream>>>(Wbf, valT, out);
}

// Round 6
// 155.760 us; speedup vs baseline: 2.1653x; 1.2235x over previous
//
#include <hip/hip_runtime.h>
#include <hip/hip_fp16.h>
#include <cstdint>

#define B_    8
#define C_    128
#define HW    4096      // 64*64
#define O_    128
#define KDIM  1152      // C_*9

typedef short bf16x8 __attribute__((ext_vector_type(8)));
typedef float f32x4  __attribute__((ext_vector_type(4)));

__device__ __forceinline__ unsigned short f2bf(float f) {
  unsigned u = __float_as_uint(f);
  u += 0x7FFFu + ((u >> 16) & 1u);
  return (unsigned short)(u >> 16);
}
__device__ __forceinline__ float bf_lo(unsigned u) { return __uint_as_float(u << 16); }
__device__ __forceinline__ float bf_hi(unsigned u) { return __uint_as_float(u & 0xFFFF0000u); }

// ---------------- workspace layout (bytes) ----------------
#define WS_WBF   0          // 128*1152*2           =   294,912
#define WS_WCB   294912     // 9*32*128*2           =    73,728
#define WS_ZERO  368640     // 256B zero row
#define WS_XT    368896     // 8*4096*128*2         = 8,388,608 -> 8,757,504
#define WS_PW    8757504    // 294912*8             = 2,359,296 -> 11,116,800
#define WS_PA    11116800   // 294912*4             = 1,179,648 -> 12,296,448
#define WS_VALT  12296448   // 8*4096*1152*2        = 75,497,472 -> 87,793,920 (< 87.8MB known-good)
#define WS_COUT  WS_VALT    // 8*4096*32*4 = 4.2MB, aliases valT (cout dead before k_sample writes)

// K0: Wbf[o][k2*128+c]; wcb[t][o][c] (o<27 from w_off/w_msk, else 0); zero row
__global__ void k_prep(const float* __restrict__ weight,
                       const float* __restrict__ w_off, const float* __restrict__ w_msk,
                       unsigned short* __restrict__ Wbf, unsigned short* __restrict__ wcb,
                       float* __restrict__ zero) {
  int gid = blockIdx.x * 256 + threadIdx.x;
  if (gid < O_ * KDIM) {
    int o = gid / KDIM, i = gid - o * KDIM;
    int k2 = i >> 7, c = i & 127;
    Wbf[gid] = f2bf(weight[o * KDIM + c * 9 + k2]);
  }
  if (gid < 9 * 32 * 128) {
    int t = gid >> 12, rem = gid & 4095;
    int o = rem >> 7, c = rem & 127;
    float v = 0.f;
    if (o < 18) v = w_off[o * KDIM + c * 9 + t];
    else if (o < 27) v = w_msk[(o - 18) * KDIM + c * 9 + t];
    wcb[gid] = f2bf(v);
  }
  if (gid < 64) zero[gid] = 0.f;
}

// K0b: transpose x[b][c][p] f32 -> xt[b][p][c] bf16
__global__ __launch_bounds__(256) void k_xt(const float* __restrict__ x,
                                            unsigned short* __restrict__ xt) {
  __shared__ unsigned short tile[64][130];   // stride 65 dwords -> conflict-free
  int bid = blockIdx.x;                      // 8 b * 64 ptiles
  int b = bid >> 6, p0 = (bid & 63) << 6;
  int tid = threadIdx.x;
  int pl = tid & 63, cq = tid >> 6;
  const float* xb = x + (size_t)b * C_ * HW + p0 + pl;
#pragma unroll
  for (int i = 0; i < 32; ++i) {
    int c = cq * 32 + i;
    tile[pl][c] = f2bf(xb[(size_t)c * HW]);
  }
  __syncthreads();
  int cd = tid & 63, pr = tid >> 6;
  unsigned* dst = (unsigned*)xt + ((size_t)b * HW + p0) * 64 + cd;
  const unsigned* t32 = (const unsigned*)&tile[0][0];
#pragma unroll
  for (int j = 0; j < 16; ++j) {
    int p = pr + j * 4;
    dst[(size_t)p * 64] = t32[p * 65 + cd];
  }
}

// K1: offset/mask conv as MFMA GEMM: cout[b][p][32] = sum_{t,c} xt[b][p+shift(t)][c] * wcb[t][o][c]
// M=128 pixels/block, N=32 (27 used), K=9 taps x 128 c, tap-double-buffered staging.
__global__ __launch_bounds__(256) void k_cgemm(const unsigned short* __restrict__ xt,
                                               const unsigned short* __restrict__ wcb,
                                               const float* __restrict__ zero,
                                               float* __restrict__ cout) {
  __shared__ __align__(16) unsigned short As[2][128 * 128];  // 32KB each
  __shared__ __align__(16) unsigned short Bs[2][32 * 128];   //  8KB each

  int bid = blockIdx.x;            // 256 = 8b * 32 ptiles
  int b = bid >> 5;
  int p0 = (bid & 31) << 7;
  int tid = threadIdx.x, lane = tid & 63, wv = tid >> 6;
  int lhi = lane >> 4, llo = lane & 15;

  const unsigned short* xb = xt + (size_t)b * HW * C_;

  auto STAGE = [&](int t, int bufi) {
    int ky = t / 3, kx = t - ky * 3;
    int dshift = (ky - 1) * 64 + (kx - 1);
#pragma unroll
    for (int i = 0; i < 8; ++i) {          // A: 128 rows x 256B = 2048 chunks
      int chunk = i * 256 + tid;
      int r = chunk >> 4, j = chunk & 15;
      int p = p0 + r;
      int ho = p >> 6, wo = p & 63;
      int iy = ho + ky - 1, ix = wo + kx - 1;
      bool valid = ((unsigned)iy < 64u) && ((unsigned)ix < 64u);
      int jj = j ^ (r & 15);               // inverse-swizzled source, linear dest
      const unsigned short* src = valid ? (xb + (size_t)(p + dshift) * C_ + jj * 8)
                                        : (const unsigned short*)zero;
      __builtin_amdgcn_global_load_lds(
          (const __attribute__((address_space(1))) unsigned*)src,
          (__attribute__((address_space(3))) unsigned*)((char*)&As[bufi][0] + i * 4096 + wv * 1024),
          16, 0, 0);
    }
#pragma unroll
    for (int i = 0; i < 2; ++i) {          // B: 32 rows x 256B = 512 chunks
      int chunk = i * 256 + tid;
      int o = chunk >> 4, j = chunk & 15;
      int jj = j ^ (o & 15);
      __builtin_amdgcn_global_load_lds(
          (const __attribute__((address_space(1))) unsigned*)(wcb + (size_t)t * 4096 + o * 128 + jj * 8),
          (__attribute__((address_space(3))) unsigned*)((char*)&Bs[bufi][0] + i * 4096 + wv * 1024),
          16, 0, 0);
    }
  };

  f32x4 acc[2][2] = {};
  STAGE(0, 0);
  __syncthreads();
  int buf = 0;
  for (int t = 0; t < 9; ++t) {
    if (t < 8) STAGE(t + 1, buf ^ 1);      // async prefetch of next tap
    bf16x8 bfv[2][4];
#pragma unroll
    for (int n = 0; n < 2; ++n)
#pragma unroll
      for (int ks = 0; ks < 4; ++ks) {
        int row = n * 16 + llo;
        int off = row * 256 + (((ks * 4 + lhi) ^ (row & 15)) << 4);
        bfv[n][ks] = *(const bf16x8*)((const char*)&Bs[buf][0] + off);
      }
#pragma unroll
    for (int ks = 0; ks < 4; ++ks) {
      bf16x8 af[2];
#pragma unroll
      for (int m = 0; m < 2; ++m) {
        int row = wv * 32 + m * 16 + llo;
        int off = row * 256 + (((ks * 4 + lhi) ^ (row & 15)) << 4);
        af[m] = *(const bf16x8*)((const char*)&As[buf][0] + off);
      }
#pragma unroll
      for (int m = 0; m < 2; ++m)
#pragma unroll
        for (int n = 0; n < 2; ++n)
          acc[m][n] = __builtin_amdgcn_mfma_f32_16x16x32_bf16(af[m], bfv[n][ks], acc[m][n], 0, 0, 0);
    }
    __syncthreads();
    buf ^= 1;
  }

  // C/D: col(lane&15)=o within n-tile, row((lane>>4)*4+reg)=pixel within m-tile
  float* cb = cout + ((size_t)b * HW + p0) * 32;
#pragma unroll
  for (int m = 0; m < 2; ++m)
#pragma unroll
    for (int n = 0; n < 2; ++n)
#pragma unroll
      for (int r = 0; r < 4; ++r) {
        int pix = wv * 32 + m * 16 + lhi * 4 + r;
        int o = n * 16 + llo;
        cb[(size_t)pix * 32 + o] = acc[m][n][r];   // o=27..31 is padding, harmless
      }
}

// K1b: bias + sigmoid + bilinear-param precompute from cout
__global__ __launch_bounds__(256) void k_rp(const float* __restrict__ cout,
                                            const float* __restrict__ b_off,
                                            const float* __restrict__ b_msk,
                                            uint2* __restrict__ pwh,
                                            unsigned* __restrict__ paw) {
  int gid = blockIdx.x * 256 + threadIdx.x;   // b*4096+p, < 32768
  int b = gid >> 12, p = gid & 4095;
  const float* cr = cout + (size_t)gid * 32;
  float v[28];
#pragma unroll
  for (int j = 0; j < 7; ++j) *(f32x4*)&v[j * 4] = *(const f32x4*)(cr + j * 4);
  int ho = p >> 6, wo = p & 63;
#pragma unroll
  for (int k2 = 0; k2 < 9; ++k2) {
    int ky = k2 / 3, kx = k2 - ky * 3;
    float dy = v[2 * k2] + b_off[2 * k2];
    float dx = v[2 * k2 + 1] + b_off[2 * k2 + 1];
    float mk = v[18 + k2] + b_msk[k2];
    mk = 1.f / (1.f + __expf(-mk));
    float py = dy + (float)(ho + ky - 1);
    float px = dx + (float)(wo + kx - 1);
    float fy = floorf(py), fx = floorf(px);
    float ly = py - fy, lx = px - fx;
    int y0 = (int)fy, x0 = (int)fx;
    float vy0 = ((unsigned)y0 < 64u) ? 1.f : 0.f;
    float vy1 = ((unsigned)(y0 + 1) < 64u) ? 1.f : 0.f;
    float vx0 = ((unsigned)x0 < 64u) ? 1.f : 0.f;
    float vx1 = ((unsigned)(x0 + 1) < 64u) ? 1.f : 0.f;
    int cy0 = min(max(y0, 0), 63);
    int cx0 = min(max(x0, 0), 63);
    float wy0 = (1.f - ly) * mk, wy1 = ly * mk;
    float w00 = wy0 * (1.f - lx) * vy0 * vx0, w01 = wy0 * lx * vy0 * vx1;
    float w10 = wy1 * (1.f - lx) * vy1 * vx0, w11 = wy1 * lx * vy1 * vx1;
    int dxf = (x0 >= 0 && x0 <= 62) ? 1 : 0;
    int dyf = (y0 >= 0 && y0 <= 62) ? 1 : 0;
    unsigned h00 = __half_as_ushort(__float2half_rn(w00));
    unsigned h01 = __half_as_ushort(__float2half_rn(w01));
    unsigned h10 = __half_as_ushort(__float2half_rn(w10));
    unsigned h11 = __half_as_ushort(__float2half_rn(w11));
    int idx = (b * 9 + k2) * HW + p;
    pwh[idx] = make_uint2(h00 | (h01 << 16), h10 | (h11 << 16));
    paw[idx] = (unsigned)(cy0 * 64 + cx0) | (dxf << 12) | (dyf << 13);
  }
}

// K2: wave per (b,p,k2); params via scalar loads; 4 coalesced 256B gathers; blend; store
__global__ __launch_bounds__(256) void k_sample(const unsigned* __restrict__ xt32,
                                                const uint2* __restrict__ pwh,
                                                const unsigned* __restrict__ paw,
                                                unsigned* __restrict__ valT32) {
  int tid = threadIdx.x;
  int lane = tid & 63;
  int wuni = __builtin_amdgcn_readfirstlane(tid >> 6);
  int task = blockIdx.x * 4 + wuni;          // wave-uniform, < 294912
  int k2 = task % 9;
  int bp = task / 9;                          // b*4096+p
  int b = bp >> 12, p = bp & 4095;
  int pidx = (b * 9 + k2) * HW + p;

  uint2 W = pwh[pidx];
  unsigned aw = paw[pidx];
  __half2 h0 = *reinterpret_cast<__half2*>(&W.x);
  __half2 h1 = *reinterpret_cast<__half2*>(&W.y);
  float2 f0 = __half22float2(h0), f1 = __half22float2(h1);
  float w00 = f0.x, w01 = f0.y, w10 = f1.x, w11 = f1.y;

  unsigned a00 = (aw & 4095u) << 6;
  unsigned dxs = ((aw >> 12) & 1u) << 6;
  unsigned dys = ((aw >> 13) & 1u) << 12;

  const unsigned* xb = xt32 + ((size_t)b << 18);
  unsigned v00 = xb[a00 + lane];
  unsigned v01 = xb[a00 + dxs + lane];
  unsigned v10 = xb[a00 + dys + lane];
  unsigned v11 = xb[a00 + dys + dxs + lane];

  float lo = w00 * bf_lo(v00) + w01 * bf_lo(v01) + w10 * bf_lo(v10) + w11 * bf_lo(v11);
  float hi = w00 * bf_hi(v00) + w01 * bf_hi(v01) + w10 * bf_hi(v10) + w11 * bf_hi(v11);
  unsigned pk = (unsigned)f2bf(lo) | ((unsigned)f2bf(hi) << 16);
  valT32[(size_t)bp * 576 + k2 * 64 + lane] = pk;
}

// K3: out[b][o][p] = sum_i Wbf[o][i] * valT[b][p][i]
__global__ __launch_bounds__(256, 2) void k_gemm(const unsigned short* __restrict__ Wbf,
                                                 const unsigned short* __restrict__ valT,
                                                 float* __restrict__ out) {
  __shared__ __align__(16) unsigned short As[2][128 * 64];
  __shared__ __align__(16) unsigned short Bs[2][64 * 64];

  int bid = blockIdx.x;            // 512 = 8b * 64 ptiles
  int b = bid >> 6;
  int pbase = (bid & 63) << 6;
  int tid = threadIdx.x, lane = tid & 63, wv = tid >> 6;
  int lhi = lane >> 4, llo = lane & 15;

  const unsigned short* vb = valT + ((size_t)b * HW + pbase) * KDIM;

  f32x4 acc[2][4] = {};

  auto STAGE = [&](int kt, int bufi) {
#pragma unroll
    for (int j = 0; j < 4; ++j) {
      int chunk = j * 256 + tid;
      int row = chunk >> 3;
      int sch = (chunk & 7) ^ (row & 7);
      __builtin_amdgcn_global_load_lds(
          (const __attribute__((address_space(1))) unsigned*)(Wbf + (size_t)row * KDIM + kt * 64 + sch * 8),
          (__attribute__((address_space(3))) unsigned*)((char*)&As[bufi][0] + j * 4096 + wv * 1024),
          16, 0, 0);
    }
#pragma unroll
    for (int j = 0; j < 2; ++j) {
      int chunk = j * 256 + tid;
      int row = chunk >> 3;
      int sch = (chunk & 7) ^ (row & 7);
      __builtin_amdgcn_global_load_lds(
          (const __attribute__((address_space(1))) unsigned*)(vb + (size_t)row * KDIM + kt * 64 + sch * 8),
          (__attribute__((address_space(3))) unsigned*)((char*)&Bs[bufi][0] + j * 4096 + wv * 1024),
          16, 0, 0);
    }
  };

  STAGE(0, 0);
  __syncthreads();

  int buf = 0;
  for (int kt = 0; kt < 18; ++kt) {
    if (kt < 17) STAGE(kt + 1, buf ^ 1);
#pragma unroll
    for (int ks = 0; ks < 2; ++ks) {
      bf16x8 af[2], bfv[4];
#pragma unroll
      for (int m = 0; m < 2; ++m) {
        int row = wv * 32 + m * 16 + llo;
        int off = row * 128 + ((ks * 64 + lhi * 16) ^ ((llo & 7) << 4));
        af[m] = *(const bf16x8*)((const char*)&As[buf][0] + off);
      }
#pragma unroll
      for (int n = 0; n < 4; ++n) {
        int row = n * 16 + llo;
        int off = row * 128 + ((ks * 64 + lhi * 16) ^ ((llo & 7) << 4));
        bfv[n] = *(const bf16x8*)((const char*)&Bs[buf][0] + off);
      }
#pragma unroll
      for (int m = 0; m < 2; ++m)
#pragma unroll
        for (int n = 0; n < 4; ++n)
          acc[m][n] = __builtin_amdgcn_mfma_f32_16x16x32_bf16(af[m], bfv[n], acc[m][n], 0, 0, 0);
    }
    __syncthreads();
    buf ^= 1;
  }

  float* ob = out + (size_t)b * O_ * HW + pbase;
#pragma unroll
  for (int m = 0; m < 2; ++m) {
    int o0 = wv * 32 + m * 16 + lhi * 4;
#pragma unroll
    for (int n = 0; n < 4; ++n) {
      int pl = n * 16 + llo;
#pragma unroll
      for (int r = 0; r < 4; ++r)
        ob[(size_t)(o0 + r) * HW + pl] = acc[m][n][r];
    }
  }
}

extern "C" void kernel_launch(void* const* d_in, const int* in_sizes, int n_in,
                              void* d_out, int out_size, void* d_ws, size_t ws_size,
                              hipStream_t stream) {
  const float* x      = (const float*)d_in[0];
  const float* w_off  = (const float*)d_in[1];
  const float* b_off  = (const float*)d_in[2];
  const float* w_msk  = (const float*)d_in[3];
  const float* b_msk  = (const float*)d_in[4];
  const float* weight = (const float*)d_in[5];
  float* out = (float*)d_out;
  char* ws = (char*)d_ws;

  unsigned short* Wbf  = (unsigned short*)(ws + WS_WBF);
  unsigned short* wcb  = (unsigned short*)(ws + WS_WCB);
  float*          zero = (float*)(ws + WS_ZERO);
  unsigned short* xt   = (unsigned short*)(ws + WS_XT);
  uint2*          pwh  = (uint2*)(ws + WS_PW);
  unsigned*       paw  = (unsigned*)(ws + WS_PA);
  float*          cgo  = (float*)(ws + WS_COUT);          // aliases valT (disjoint lifetime)
  unsigned short* valT = (unsigned short*)(ws + WS_VALT);

  k_prep  <<<576, 256, 0, stream>>>(weight, w_off, w_msk, Wbf, wcb, zero);
  k_xt    <<<512, 256, 0, stream>>>(x, xt);
  k_cgemm <<<256, 256, 0, stream>>>(xt, wcb, zero, cgo);
  k_rp    <<<128, 256, 0, stream>>>(cgo, b_off, b_msk, pwh, paw);
  k_sample<<<73728, 256, 0, stream>>>((const unsigned*)xt, pwh, paw, (unsigned*)valT);
  k_gemm  <<<512, 256, 0, stream>>>(Wbf, valT, out);
}

// Round 7
// 132.394 us; speedup vs baseline: 2.5475x; 1.1765x over previous
//
#include <hip/hip_runtime.h>
#include <hip/hip_fp16.h>
#include <cstdint>

#define B_    8
#define C_    128
#define HW    4096      // 64*64
#define O_    128
#define KDIM  1152      // C_*9

typedef short bf16x8 __attribute__((ext_vector_type(8)));
typedef float f32x4  __attribute__((ext_vector_type(4)));

__device__ __forceinline__ unsigned short f2bf(float f) {
  unsigned u = __float_as_uint(f);
  u += 0x7FFFu + ((u >> 16) & 1u);
  return (unsigned short)(u >> 16);
}
__device__ __forceinline__ float bf_lo(unsigned u) { return __uint_as_float(u << 16); }
__device__ __forceinline__ float bf_hi(unsigned u) { return __uint_as_float(u & 0xFFFF0000u); }

// ---------------- workspace layout (bytes) ----------------
#define WS_WBF   0          // 128*1152*2           =   294,912
#define WS_WCB   294912     // 9*32*128*2           =    73,728
#define WS_ZERO  368640     // 256B zero row
#define WS_XT    368896     // 8*4096*128*2         = 8,388,608 -> 8,757,504
#define WS_PW    8757504    // 294912*8             = 2,359,296 -> 11,116,800
#define WS_PA    11116800   // 294912*4             = 1,179,648 -> 12,296,448
#define WS_COUT  12296448   // 8*4096*32*4          = 4,194,304 -> 16,490,752

// K0: Wbf[o][k2*128+c]; wcb[t][o][c]; zero row
__global__ void k_prep(const float* __restrict__ weight,
                       const float* __restrict__ w_off, const float* __restrict__ w_msk,
                       unsigned short* __restrict__ Wbf, unsigned short* __restrict__ wcb,
                       float* __restrict__ zero) {
  int gid = blockIdx.x * 256 + threadIdx.x;
  if (gid < O_ * KDIM) {
    int o = gid / KDIM, i = gid - o * KDIM;
    int k2 = i >> 7, c = i & 127;
    Wbf[gid] = f2bf(weight[o * KDIM + c * 9 + k2]);
  }
  if (gid < 9 * 32 * 128) {
    int t = gid >> 12, rem = gid & 4095;
    int o = rem >> 7, c = rem & 127;
    float v = 0.f;
    if (o < 18) v = w_off[o * KDIM + c * 9 + t];
    else if (o < 27) v = w_msk[(o - 18) * KDIM + c * 9 + t];
    wcb[gid] = f2bf(v);
  }
  if (gid < 64) zero[gid] = 0.f;
}

// K0b: transpose x[b][c][p] f32 -> xt[b][p][c] bf16
__global__ __launch_bounds__(256) void k_xt(const float* __restrict__ x,
                                            unsigned short* __restrict__ xt) {
  __shared__ unsigned short tile[64][130];
  int bid = blockIdx.x;                      // 8 b * 64 ptiles
  int b = bid >> 6, p0 = (bid & 63) << 6;
  int tid = threadIdx.x;
  int pl = tid & 63, cq = tid >> 6;
  const float* xb = x + (size_t)b * C_ * HW + p0 + pl;
#pragma unroll
  for (int i = 0; i < 32; ++i) {
    int c = cq * 32 + i;
    tile[pl][c] = f2bf(xb[(size_t)c * HW]);
  }
  __syncthreads();
  int cd = tid & 63, pr = tid >> 6;
  unsigned* dst = (unsigned*)xt + ((size_t)b * HW + p0) * 64 + cd;
  const unsigned* t32 = (const unsigned*)&tile[0][0];
#pragma unroll
  for (int j = 0; j < 16; ++j) {
    int p = pr + j * 4;
    dst[(size_t)p * 64] = t32[p * 65 + cd];
  }
}

// K1: offset/mask conv as MFMA GEMM: cout[b][p][32]
__global__ __launch_bounds__(256) void k_cgemm(const unsigned short* __restrict__ xt,
                                               const unsigned short* __restrict__ wcb,
                                               const float* __restrict__ zero,
                                               float* __restrict__ cout) {
  __shared__ __align__(16) unsigned short As[2][128 * 128];
  __shared__ __align__(16) unsigned short Bs[2][32 * 128];

  int bid = blockIdx.x;            // 256 = 8b * 32 ptiles
  int b = bid >> 5;
  int p0 = (bid & 31) << 7;
  int tid = threadIdx.x, lane = tid & 63, wv = tid >> 6;
  int lhi = lane >> 4, llo = lane & 15;

  const unsigned short* xb = xt + (size_t)b * HW * C_;

  auto STAGE = [&](int t, int bufi) {
    int ky = t / 3, kx = t - ky * 3;
    int dshift = (ky - 1) * 64 + (kx - 1);
#pragma unroll
    for (int i = 0; i < 8; ++i) {
      int chunk = i * 256 + tid;
      int r = chunk >> 4, j = chunk & 15;
      int p = p0 + r;
      int ho = p >> 6, wo = p & 63;
      int iy = ho + ky - 1, ix = wo + kx - 1;
      bool valid = ((unsigned)iy < 64u) && ((unsigned)ix < 64u);
      int jj = j ^ (r & 15);
      const unsigned short* src = valid ? (xb + (size_t)(p + dshift) * C_ + jj * 8)
                                        : (const unsigned short*)zero;
      __builtin_amdgcn_global_load_lds(
          (const __attribute__((address_space(1))) unsigned*)src,
          (__attribute__((address_space(3))) unsigned*)((char*)&As[bufi][0] + i * 4096 + wv * 1024),
          16, 0, 0);
    }
#pragma unroll
    for (int i = 0; i < 2; ++i) {
      int chunk = i * 256 + tid;
      int o = chunk >> 4, j = chunk & 15;
      int jj = j ^ (o & 15);
      __builtin_amdgcn_global_load_lds(
          (const __attribute__((address_space(1))) unsigned*)(wcb + (size_t)t * 4096 + o * 128 + jj * 8),
          (__attribute__((address_space(3))) unsigned*)((char*)&Bs[bufi][0] + i * 4096 + wv * 1024),
          16, 0, 0);
    }
  };

  f32x4 acc[2][2] = {};
  STAGE(0, 0);
  __syncthreads();
  int buf = 0;
  for (int t = 0; t < 9; ++t) {
    if (t < 8) STAGE(t + 1, buf ^ 1);
    bf16x8 bfv[2][4];
#pragma unroll
    for (int n = 0; n < 2; ++n)
#pragma unroll
      for (int ks = 0; ks < 4; ++ks) {
        int row = n * 16 + llo;
        int off = row * 256 + (((ks * 4 + lhi) ^ (row & 15)) << 4);
        bfv[n][ks] = *(const bf16x8*)((const char*)&Bs[buf][0] + off);
      }
#pragma unroll
    for (int ks = 0; ks < 4; ++ks) {
      bf16x8 af[2];
#pragma unroll
      for (int m = 0; m < 2; ++m) {
        int row = wv * 32 + m * 16 + llo;
        int off = row * 256 + (((ks * 4 + lhi) ^ (row & 15)) << 4);
        af[m] = *(const bf16x8*)((const char*)&As[buf][0] + off);
      }
#pragma unroll
      for (int m = 0; m < 2; ++m)
#pragma unroll
        for (int n = 0; n < 2; ++n)
          acc[m][n] = __builtin_amdgcn_mfma_f32_16x16x32_bf16(af[m], bfv[n][ks], acc[m][n], 0, 0, 0);
    }
    __syncthreads();
    buf ^= 1;
  }

  float* cb = cout + ((size_t)b * HW + p0) * 32;
#pragma unroll
  for (int m = 0; m < 2; ++m)
#pragma unroll
    for (int n = 0; n < 2; ++n)
#pragma unroll
      for (int r = 0; r < 4; ++r) {
        int pix = wv * 32 + m * 16 + lhi * 4 + r;
        int o = n * 16 + llo;
        cb[(size_t)pix * 32 + o] = acc[m][n][r];
      }
}

// K1b: bias + sigmoid + bilinear-param precompute from cout
__global__ __launch_bounds__(256) void k_rp(const float* __restrict__ cout,
                                            const float* __restrict__ b_off,
                                            const float* __restrict__ b_msk,
                                            uint2* __restrict__ pwh,
                                            unsigned* __restrict__ paw) {
  int gid = blockIdx.x * 256 + threadIdx.x;   // b*4096+p, < 32768
  int b = gid >> 12, p = gid & 4095;
  const float* cr = cout + (size_t)gid * 32;
  float v[28];
#pragma unroll
  for (int j = 0; j < 7; ++j) *(f32x4*)&v[j * 4] = *(const f32x4*)(cr + j * 4);
  int ho = p >> 6, wo = p & 63;
#pragma unroll
  for (int k2 = 0; k2 < 9; ++k2) {
    int ky = k2 / 3, kx = k2 - ky * 3;
    float dy = v[2 * k2] + b_off[2 * k2];
    float dx = v[2 * k2 + 1] + b_off[2 * k2 + 1];
    float mk = v[18 + k2] + b_msk[k2];
    mk = 1.f / (1.f + __expf(-mk));
    float py = dy + (float)(ho + ky - 1);
    float px = dx + (float)(wo + kx - 1);
    float fy = floorf(py), fx = floorf(px);
    float ly = py - fy, lx = px - fx;
    int y0 = (int)fy, x0 = (int)fx;
    float vy0 = ((unsigned)y0 < 64u) ? 1.f : 0.f;
    float vy1 = ((unsigned)(y0 + 1) < 64u) ? 1.f : 0.f;
    float vx0 = ((unsigned)x0 < 64u) ? 1.f : 0.f;
    float vx1 = ((unsigned)(x0 + 1) < 64u) ? 1.f : 0.f;
    int cy0 = min(max(y0, 0), 63);
    int cx0 = min(max(x0, 0), 63);
    float wy0 = (1.f - ly) * mk, wy1 = ly * mk;
    float w00 = wy0 * (1.f - lx) * vy0 * vx0, w01 = wy0 * lx * vy0 * vx1;
    float w10 = wy1 * (1.f - lx) * vy1 * vx0, w11 = wy1 * lx * vy1 * vx1;
    int dxf = (x0 >= 0 && x0 <= 62) ? 1 : 0;
    int dyf = (y0 >= 0 && y0 <= 62) ? 1 : 0;
    unsigned h00 = __half_as_ushort(__float2half_rn(w00));
    unsigned h01 = __half_as_ushort(__float2half_rn(w01));
    unsigned h10 = __half_as_ushort(__float2half_rn(w10));
    unsigned h11 = __half_as_ushort(__float2half_rn(w11));
    int idx = (b * 9 + k2) * HW + p;
    pwh[idx] = make_uint2(h00 | (h01 << 16), h10 | (h11 << 16));
    paw[idx] = (unsigned)(cy0 * 64 + cx0) | (dxf << 12) | (dyf << 13);
  }
}

// K2: fused sample+GEMM. Block = 64 pixels x all 128 outputs; val built in LDS per tap.
// out[b][o][p] = sum_{k2,c} Wbf[o][k2*128+c] * val[p][k2*128+c]
__global__ __launch_bounds__(256) void k_fused(const unsigned* __restrict__ xt32,
                                               const uint2* __restrict__ pwh,
                                               const unsigned* __restrict__ paw,
                                               const unsigned short* __restrict__ Wbf,
                                               float* __restrict__ out) {
  __shared__ __align__(16) unsigned short As[2][128 * 64];   // 16KB x2: Wbf k-step tiles
  __shared__ __align__(16) unsigned short Bs[2][64 * 128];   // 16KB x2: val tap tiles

  int bid = blockIdx.x;            // 512 = 8b * 64 ptiles
  int b = bid >> 6;
  int pbase = (bid & 63) << 6;
  int tid = threadIdx.x, lane = tid & 63;
  int wuni = __builtin_amdgcn_readfirstlane(tid >> 6);
  int wr = wuni >> 1, wc = wuni & 1;
  int lhi = lane >> 4, llo = lane & 15;

  const unsigned* xb32 = xt32 + ((size_t)b << 18);   // b*4096*64 u32

  uint2 Wv[8]; unsigned awv[8]; unsigned g[32];

  auto B_ISSUE = [&](int k2n, int half) {            // params + 32 gathers for 8 pixels
    int pp0 = wuni * 16 + half * 8;
    int pidx0 = (b * 9 + k2n) * HW + pbase + pp0;    // wave-uniform -> scalar loads
#pragma unroll
    for (int i = 0; i < 8; ++i) { Wv[i] = pwh[pidx0 + i]; awv[i] = paw[pidx0 + i]; }
#pragma unroll
    for (int i = 0; i < 8; ++i) {
      unsigned aw = awv[i];
      unsigned a00 = (aw & 4095u) << 6;
      unsigned dxs = ((aw >> 12) & 1u) << 6;
      unsigned dys = ((aw >> 13) & 1u) << 12;
      g[i * 4 + 0] = xb32[a00 + lane];
      g[i * 4 + 1] = xb32[a00 + dxs + lane];
      g[i * 4 + 2] = xb32[a00 + dys + lane];
      g[i * 4 + 3] = xb32[a00 + dys + dxs + lane];
    }
  };
  auto B_FIN = [&](int bufn, int half) {             // blend + swizzled ds_write
#pragma unroll
    for (int i = 0; i < 8; ++i) {
      float2 f0 = __half22float2(*reinterpret_cast<__half2*>(&Wv[i].x));
      float2 f1 = __half22float2(*reinterpret_cast<__half2*>(&Wv[i].y));
      unsigned v00 = g[i*4], v01 = g[i*4+1], v10 = g[i*4+2], v11 = g[i*4+3];
      float lo = f0.x*bf_lo(v00) + f0.y*bf_lo(v01) + f1.x*bf_lo(v10) + f1.y*bf_lo(v11);
      float hi = f0.x*bf_hi(v00) + f0.y*bf_hi(v01) + f1.x*bf_hi(v10) + f1.y*bf_hi(v11);
      unsigned pk = (unsigned)f2bf(lo) | ((unsigned)f2bf(hi) << 16);
      int row = wuni * 16 + half * 8 + i;
      unsigned off = (unsigned)(row * 256) + (((unsigned)lane * 4u) ^ ((unsigned)(row & 7) << 4));
      *(unsigned*)((char*)&Bs[bufn][0] + off) = pk;
    }
  };
  auto STAGE_A = [&](int kt, int abuf) {             // Wbf[128][kt*64..] via glds+swizzle
#pragma unroll
    for (int j = 0; j < 4; ++j) {
      int chunk = j * 256 + tid;
      int row = chunk >> 3;
      int sch = (chunk & 7) ^ (row & 7);
      __builtin_amdgcn_global_load_lds(
          (const __attribute__((address_space(1))) unsigned*)(Wbf + (size_t)row * KDIM + kt * 64 + sch * 8),
          (__attribute__((address_space(3))) unsigned*)((char*)&As[abuf][0] + j * 4096 + wuni * 1024),
          16, 0, 0);
    }
  };

  f32x4 acc[4][2] = {};
  auto MSTEP = [&](int abuf, int bbuf, int bhalf) {
#pragma unroll
    for (int ks = 0; ks < 2; ++ks) {
      bf16x8 af[4], bfv[2];
#pragma unroll
      for (int m = 0; m < 4; ++m) {
        int row = wr * 64 + m * 16 + llo;
        int off = row * 128 + ((ks * 64 + lhi * 16) ^ ((llo & 7) << 4));
        af[m] = *(const bf16x8*)((const char*)&As[abuf][0] + off);
      }
#pragma unroll
      for (int n = 0; n < 2; ++n) {
        int row = wc * 32 + n * 16 + llo;
        int off = row * 256 + ((bhalf * 128 + ks * 64 + lhi * 16) ^ ((row & 7) << 4));
        bfv[n] = *(const bf16x8*)((const char*)&Bs[bbuf][0] + off);
      }
#pragma unroll
      for (int m = 0; m < 4; ++m)
#pragma unroll
        for (int n = 0; n < 2; ++n)
          acc[m][n] = __builtin_amdgcn_mfma_f32_16x16x32_bf16(af[m], bfv[n], acc[m][n], 0, 0, 0);
    }
  };

  // prologue: build tap-0 val tile, stage first Wbf k-step
  B_ISSUE(0, 0); B_FIN(0, 0);
  B_ISSUE(0, 1); B_FIN(0, 1);
  STAGE_A(0, 0);
  __syncthreads();

  for (int k2 = 0; k2 < 9; ++k2) {
    int kt0 = 2 * k2;
    // even phase: MFMA on half 0 of current tap; prefetch A(kt0+1); build next-tap half 0
    if (kt0 + 1 < 18) STAGE_A(kt0 + 1, (kt0 + 1) & 1);
    if (k2 < 8) B_ISSUE(k2 + 1, 0);            // gathers in flight across MFMA (T14)
    MSTEP(kt0 & 1, k2 & 1, 0);
    if (k2 < 8) B_FIN((k2 + 1) & 1, 0);
    __syncthreads();
    // odd phase
    if (kt0 + 2 < 18) STAGE_A(kt0 + 2, (kt0 + 2) & 1);
    if (k2 < 8) B_ISSUE(k2 + 1, 1);
    MSTEP((kt0 + 1) & 1, k2 & 1, 1);
    if (k2 < 8) B_FIN((k2 + 1) & 1, 1);
    __syncthreads();
  }

  float* ob = out + (size_t)b * O_ * HW + pbase;
#pragma unroll
  for (int m = 0; m < 4; ++m) {
    int o0 = wr * 64 + m * 16 + lhi * 4;
#pragma unroll
    for (int n = 0; n < 2; ++n) {
      int px = wc * 32 + n * 16 + llo;
#pragma unroll
      for (int r = 0; r < 4; ++r)
        ob[(size_t)(o0 + r) * HW + px] = acc[m][n][r];
    }
  }
}

extern "C" void kernel_launch(void* const* d_in, const int* in_sizes, int n_in,
                              void* d_out, int out_size, void* d_ws, size_t ws_size,
                              hipStream_t stream) {
  const float* x      = (const float*)d_in[0];
  const float* w_off  = (const float*)d_in[1];
  const float* b_off  = (const float*)d_in[2];
  const float* w_msk  = (const float*)d_in[3];
  const float* b_msk  = (const float*)d_in[4];
  const float* weight = (const float*)d_in[5];
  float* out = (float*)d_out;
  char* ws = (char*)d_ws;

  unsigned short* Wbf  = (unsigned short*)(ws + WS_WBF);
  unsigned short* wcb  = (unsigned short*)(ws + WS_WCB);
  float*          zero = (float*)(ws + WS_ZERO);
  unsigned short* xt   = (unsigned short*)(ws + WS_XT);
  uint2*          pwh  = (uint2*)(ws + WS_PW);
  unsigned*       paw  = (unsigned*)(ws + WS_PA);
  float*          cgo  = (float*)(ws + WS_COUT);

  k_prep  <<<576, 256, 0, stream>>>(weight, w_off, w_msk, Wbf, wcb, zero);
  k_xt    <<<512, 256, 0, stream>>>(x, xt);
  k_cgemm <<<256, 256, 0, stream>>>(xt, wcb, zero, cgo);
  k_rp    <<<128, 256, 0, stream>>>(cgo, b_off, b_msk, pwh, paw);
  k_fused <<<512, 256, 0, stream>>>((const unsigned*)xt, pwh, paw, Wbf, out);
}

// Round 11
// 131.839 us; speedup vs baseline: 2.5582x; 1.0042x over previous
//
#include <hip/hip_runtime.h>
#include <hip/hip_fp16.h>
#include <cstdint>

#define B_    8
#define C_    128
#define HW    4096      // 64*64
#define O_    128
#define KDIM  1152      // C_*9

typedef short bf16x8 __attribute__((ext_vector_type(8)));
typedef float f32x4  __attribute__((ext_vector_type(4)));

__device__ __forceinline__ unsigned short f2bf(float f) {
  unsigned u = __float_as_uint(f);
  u += 0x7FFFu + ((u >> 16) & 1u);
  return (unsigned short)(u >> 16);
}
__device__ __forceinline__ float bf_lo(unsigned u) { return __uint_as_float(u << 16); }
__device__ __forceinline__ float bf_hi(unsigned u) { return __uint_as_float(u & 0xFFFF0000u); }

// ---------------- workspace layout (bytes) ----------------
#define WS_WBF   0          // 128*1152*2           =   294,912
#define WS_WCB   294912     // 9*32*128*2           =    73,728
#define WS_ZERO  368640     // 256B zero row
#define WS_XT    368896     // 8*4096*128*2         = 8,388,608 -> 8,757,504
#define WS_PW    8757504    // 294912*8             = 2,359,296 -> 11,116,800
#define WS_PA    11116800   // 294912*4             = 1,179,648 -> 12,296,448
#define WS_COUT  12296448   // 8*4096*32*4          = 4,194,304 -> 16,490,752

// K0 merged: [bid<576] Wbf/wcb/zero prep ; [bid>=576] x -> xt transpose
__global__ __launch_bounds__(256) void k_px(const float* __restrict__ weight,
                                            const float* __restrict__ w_off,
                                            const float* __restrict__ w_msk,
                                            const float* __restrict__ x,
                                            unsigned short* __restrict__ Wbf,
                                            unsigned short* __restrict__ wcb,
                                            float* __restrict__ zero,
                                            unsigned short* __restrict__ xt) {
  __shared__ unsigned short tile[64][130];
  int bid = blockIdx.x;
  int tid = threadIdx.x;
  if (bid < 576) {
    int gid = bid * 256 + tid;
    if (gid < O_ * KDIM) {
      int o = gid / KDIM, i = gid - o * KDIM;
      int k2 = i >> 7, c = i & 127;
      Wbf[gid] = f2bf(weight[o * KDIM + c * 9 + k2]);
    }
    if (gid < 9 * 32 * 128) {
      int t = gid >> 12, rem = gid & 4095;
      int o = rem >> 7, c = rem & 127;
      float v = 0.f;
      if (o < 18) v = w_off[o * KDIM + c * 9 + t];
      else if (o < 27) v = w_msk[(o - 18) * KDIM + c * 9 + t];
      wcb[gid] = f2bf(v);
    }
    if (gid < 64) zero[gid] = 0.f;
    return;
  }
  int xb_id = bid - 576;                     // 512 = 8b * 64 ptiles
  int b = xb_id >> 6, p0 = (xb_id & 63) << 6;
  int pl = tid & 63, cq = tid >> 6;
  const float* xb = x + (size_t)b * C_ * HW + p0 + pl;
#pragma unroll
  for (int i = 0; i < 32; ++i) {
    int c = cq * 32 + i;
    tile[pl][c] = f2bf(xb[(size_t)c * HW]);
  }
  __syncthreads();
  int cd = tid & 63, pr = tid >> 6;
  unsigned* dst = (unsigned*)xt + ((size_t)b * HW + p0) * 64 + cd;
  const unsigned* t32 = (const unsigned*)&tile[0][0];
#pragma unroll
  for (int j = 0; j < 16; ++j) {
    int p = pr + j * 4;
    dst[(size_t)p * 64] = t32[p * 65 + cd];
  }
}

// K1: offset/mask conv as MFMA GEMM: cout[b][p][32]
__global__ __launch_bounds__(256) void k_cgemm(const unsigned short* __restrict__ xt,
                                               const unsigned short* __restrict__ wcb,
                                               const float* __restrict__ zero,
                                               float* __restrict__ cout) {
  __shared__ __align__(16) unsigned short As[2][128 * 128];
  __shared__ __align__(16) unsigned short Bs[2][32 * 128];

  int bid = blockIdx.x;            // 256 = 8b * 32 ptiles
  int b = bid >> 5;
  int p0 = (bid & 31) << 7;
  int tid = threadIdx.x, lane = tid & 63, wv = tid >> 6;
  int lhi = lane >> 4, llo = lane & 15;

  const unsigned short* xb = xt + (size_t)b * HW * C_;

  auto STAGE = [&](int t, int bufi) {
    int ky = t / 3, kx = t - ky * 3;
    int dshift = (ky - 1) * 64 + (kx - 1);
#pragma unroll
    for (int i = 0; i < 8; ++i) {
      int chunk = i * 256 + tid;
      int r = chunk >> 4, j = chunk & 15;
      int p = p0 + r;
      int ho = p >> 6, wo = p & 63;
      int iy = ho + ky - 1, ix = wo + kx - 1;
      bool valid = ((unsigned)iy < 64u) && ((unsigned)ix < 64u);
      int jj = j ^ (r & 15);
      const unsigned short* src = valid ? (xb + (size_t)(p + dshift) * C_ + jj * 8)
                                        : (const unsigned short*)zero;
      __builtin_amdgcn_global_load_lds(
          (const __attribute__((address_space(1))) unsigned*)src,
          (__attribute__((address_space(3))) unsigned*)((char*)&As[bufi][0] + i * 4096 + wv * 1024),
          16, 0, 0);
    }
#pragma unroll
    for (int i = 0; i < 2; ++i) {
      int chunk = i * 256 + tid;
      int o = chunk >> 4, j = chunk & 15;
      int jj = j ^ (o & 15);
      __builtin_amdgcn_global_load_lds(
          (const __attribute__((address_space(1))) unsigned*)(wcb + (size_t)t * 4096 + o * 128 + jj * 8),
          (__attribute__((address_space(3))) unsigned*)((char*)&Bs[bufi][0] + i * 4096 + wv * 1024),
          16, 0, 0);
    }
  };

  f32x4 acc[2][2] = {};
  STAGE(0, 0);
  __syncthreads();
  int buf = 0;
  for (int t = 0; t < 9; ++t) {
    if (t < 8) STAGE(t + 1, buf ^ 1);
    bf16x8 bfv[2][4];
#pragma unroll
    for (int n = 0; n < 2; ++n)
#pragma unroll
      for (int ks = 0; ks < 4; ++ks) {
        int row = n * 16 + llo;
        int off = row * 256 + (((ks * 4 + lhi) ^ (row & 15)) << 4);
        bfv[n][ks] = *(const bf16x8*)((const char*)&Bs[buf][0] + off);
      }
#pragma unroll
    for (int ks = 0; ks < 4; ++ks) {
      bf16x8 af[2];
#pragma unroll
      for (int m = 0; m < 2; ++m) {
        int row = wv * 32 + m * 16 + llo;
        int off = row * 256 + (((ks * 4 + lhi) ^ (row & 15)) << 4);
        af[m] = *(const bf16x8*)((const char*)&As[buf][0] + off);
      }
#pragma unroll
      for (int m = 0; m < 2; ++m)
#pragma unroll
        for (int n = 0; n < 2; ++n)
          acc[m][n] = __builtin_amdgcn_mfma_f32_16x16x32_bf16(af[m], bfv[n][ks], acc[m][n], 0, 0, 0);
    }
    __syncthreads();
    buf ^= 1;
  }

  float* cb = cout + ((size_t)b * HW + p0) * 32;
#pragma unroll
  for (int m = 0; m < 2; ++m)
#pragma unroll
    for (int n = 0; n < 2; ++n)
#pragma unroll
      for (int r = 0; r < 4; ++r) {
        int pix = wv * 32 + m * 16 + lhi * 4 + r;
        int o = n * 16 + llo;
        cb[(size_t)pix * 32 + o] = acc[m][n][r];
      }
}

// K1b: bias + sigmoid + bilinear params, one thread per (b,k2,p)
__global__ __launch_bounds__(256) void k_rp(const float* __restrict__ cout,
                                            const float* __restrict__ b_off,
                                            const float* __restrict__ b_msk,
                                            uint2* __restrict__ pwh,
                                            unsigned* __restrict__ paw) {
  int gid = blockIdx.x * 256 + threadIdx.x;   // < 294912, = (b*9+k2)*4096 + p
  int p = gid & 4095;
  int bk = gid >> 12;                          // block-uniform
  int b = bk / 9, k2 = bk - 9 * b;
  const float* cr = cout + ((size_t)b * HW + p) * 32;
  float dy = cr[2 * k2]     + b_off[2 * k2];
  float dx = cr[2 * k2 + 1] + b_off[2 * k2 + 1];
  float mk = cr[18 + k2]    + b_msk[k2];
  mk = 1.f / (1.f + __expf(-mk));
  int ho = p >> 6, wo = p & 63;
  int ky = k2 / 3, kx = k2 - ky * 3;
  float py = dy + (float)(ho + ky - 1);
  float px = dx + (float)(wo + kx - 1);
  float fy = floorf(py), fx = floorf(px);
  float ly = py - fy, lx = px - fx;
  int y0 = (int)fy, x0 = (int)fx;
  float vy0 = ((unsigned)y0 < 64u) ? 1.f : 0.f;
  float vy1 = ((unsigned)(y0 + 1) < 64u) ? 1.f : 0.f;
  float vx0 = ((unsigned)x0 < 64u) ? 1.f : 0.f;
  float vx1 = ((unsigned)(x0 + 1) < 64u) ? 1.f : 0.f;
  int cy0 = min(max(y0, 0), 63);
  int cx0 = min(max(x0, 0), 63);
  float wy0 = (1.f - ly) * mk, wy1 = ly * mk;
  float w00 = wy0 * (1.f - lx) * vy0 * vx0, w01 = wy0 * lx * vy0 * vx1;
  float w10 = wy1 * (1.f - lx) * vy1 * vx0, w11 = wy1 * lx * vy1 * vx1;
  int dxf = (x0 >= 0 && x0 <= 62) ? 1 : 0;
  int dyf = (y0 >= 0 && y0 <= 62) ? 1 : 0;
  unsigned h00 = __half_as_ushort(__float2half_rn(w00));
  unsigned h01 = __half_as_ushort(__float2half_rn(w01));
  unsigned h10 = __half_as_ushort(__float2half_rn(w10));
  unsigned h11 = __half_as_ushort(__float2half_rn(w11));
  pwh[gid] = make_uint2(h00 | (h01 << 16), h10 | (h11 << 16));
  paw[gid] = (unsigned)(cy0 * 64 + cx0) | (dxf << 12) | (dyf << 13);
}

// K2: fused sample+GEMM, 18 half-tap phases, 3 B-buffers, raw barriers + counted waits.
// Pipeline per phase p: MSTEP consumes q=p; FIN writes q=p+2 (gathers issued phase p-1);
// ISSUE launches q=p+3; PARAMS loads q=p+4. Prologue must ISSUE q=0,1 AND q=2.
__global__ __launch_bounds__(256, 2) void k_fused(const unsigned* __restrict__ xt32,
                                                  const uint2* __restrict__ pwh,
                                                  const unsigned* __restrict__ paw,
                                                  const unsigned short* __restrict__ Wbf,
                                                  float* __restrict__ out) {
  __shared__ __align__(16) unsigned short As[2][128 * 64];   // 16KB x2: Wbf K-step tiles
  __shared__ __align__(16) unsigned short Bs[3][64 * 128];   // 16KB x3: val tap tiles

  int bid = blockIdx.x;            // 512 = 8b * 64 ptiles
  int b = bid >> 6;
  int pbase = (bid & 63) << 6;
  int tid = threadIdx.x, lane = tid & 63;
  int wuni = __builtin_amdgcn_readfirstlane(tid >> 6);
  int wr = wuni >> 1, wc = wuni & 1;
  int lhi = lane >> 4, llo = lane & 15;

  const unsigned* xb32 = xt32 + ((size_t)b << 18);

  // param sets (wave-uniform) and gather sets, all const-indexed
  uint2 Wv[2][8]; unsigned Av[2][8]; unsigned g[2][32];

  auto PARAMS = [&](int q, int s) {         // load params for half-tap q into set s
    int tap = q >> 1, half = q & 1;
    int base = (b * 9 + tap) * HW + pbase + wuni * 16 + half * 8;   // uniform
#pragma unroll
    for (int i = 0; i < 8; ++i) { Wv[s][i] = pwh[base + i]; Av[s][i] = paw[base + i]; }
  };
  auto ISSUE = [&](int s) {                 // 32 gathers from set s params
#pragma unroll
    for (int i = 0; i < 8; ++i) {
      unsigned aw = Av[s][i];
      unsigned a00 = (aw & 4095u) << 6;
      unsigned dxs = ((aw >> 12) & 1u) << 6;
      unsigned dys = ((aw >> 13) & 1u) << 12;
      g[s][i * 4 + 0] = xb32[a00 + lane];
      g[s][i * 4 + 1] = xb32[a00 + dxs + lane];
      g[s][i * 4 + 2] = xb32[a00 + dys + lane];
      g[s][i * 4 + 3] = xb32[a00 + dys + dxs + lane];
    }
  };
  auto FIN = [&](int s, int bufn, int half) {  // blend + swizzled ds_write (8 rows)
#pragma unroll
    for (int i = 0; i < 8; ++i) {
      float2 f0 = __half22float2(*reinterpret_cast<__half2*>(&Wv[s][i].x));
      float2 f1 = __half22float2(*reinterpret_cast<__half2*>(&Wv[s][i].y));
      unsigned v00 = g[s][i*4], v01 = g[s][i*4+1], v10 = g[s][i*4+2], v11 = g[s][i*4+3];
      float lo = f0.x*bf_lo(v00) + f0.y*bf_lo(v01) + f1.x*bf_lo(v10) + f1.y*bf_lo(v11);
      float hi = f0.x*bf_hi(v00) + f0.y*bf_hi(v01) + f1.x*bf_hi(v10) + f1.y*bf_hi(v11);
      unsigned pk = (unsigned)f2bf(lo) | ((unsigned)f2bf(hi) << 16);
      int row = wuni * 16 + half * 8 + i;
      unsigned off = (unsigned)(row * 256) + (((unsigned)lane * 4u) ^ ((unsigned)(row & 7) << 4));
      *(unsigned*)((char*)&Bs[bufn][0] + off) = pk;
    }
  };
  auto STAGE_A = [&](int kt, int abuf) {    // Wbf K-step via glds + swizzle
#pragma unroll
    for (int j = 0; j < 4; ++j) {
      int chunk = j * 256 + tid;
      int row = chunk >> 3;
      int sch = (chunk & 7) ^ (row & 7);
      __builtin_amdgcn_global_load_lds(
          (const __attribute__((address_space(1))) unsigned*)(Wbf + (size_t)row * KDIM + kt * 64 + sch * 8),
          (__attribute__((address_space(3))) unsigned*)((char*)&As[abuf][0] + j * 4096 + wuni * 1024),
          16, 0, 0);
    }
  };

  f32x4 acc[4][2] = {};
  auto MSTEP = [&](int abuf, int bbuf, int kh) {
    __builtin_amdgcn_s_setprio(1);
#pragma unroll
    for (int ks = 0; ks < 2; ++ks) {
      bf16x8 af[4], bfv[2];
#pragma unroll
      for (int m = 0; m < 4; ++m) {
        int row = wr * 64 + m * 16 + llo;
        int off = row * 128 + ((ks * 64 + lhi * 16) ^ ((llo & 7) << 4));
        af[m] = *(const bf16x8*)((const char*)&As[abuf][0] + off);
      }
#pragma unroll
      for (int n = 0; n < 2; ++n) {
        int row = wc * 32 + n * 16 + llo;
        int off = row * 256 + ((kh * 128 + ks * 64 + lhi * 16) ^ ((row & 7) << 4));
        bfv[n] = *(const bf16x8*)((const char*)&Bs[bbuf][0] + off);
      }
#pragma unroll
      for (int m = 0; m < 4; ++m)
#pragma unroll
        for (int n = 0; n < 2; ++n)
          acc[m][n] = __builtin_amdgcn_mfma_f32_16x16x32_bf16(af[m], bfv[n], acc[m][n], 0, 0, 0);
    }
    __builtin_amdgcn_s_setprio(0);
  };

  // prologue: q=0,1 built into Bs[0]; q=2 params+gathers in flight; A k-step 0 staged
  PARAMS(0, 0); PARAMS(1, 1);
  ISSUE(0); ISSUE(1);
  FIN(0, 0, 0);                 // q=0 -> Bs[0] half0 (frees g[0])
  PARAMS(2, 0);                 // q=2 params -> set 0
  FIN(1, 0, 1);                 // q=1 -> Bs[0] half1
  PARAMS(3, 1);                 // q=3 params -> set 1
  ISSUE(0);                     // q=2 gathers -> g[0]   [r8 BUG: this was missing]
  STAGE_A(0, 0);
  __syncthreads();              // one-time full drain

  // phases p=0..17
#pragma unroll 6
  for (int p = 0; p < 18; ++p) {
    if (p + 1 < 18) STAGE_A(p + 1, (p + 1) & 1);
    __builtin_amdgcn_sched_barrier(0);        // keep A-glds oldest in vmcnt order
    if (p + 3 < 18) ISSUE((p + 1) & 1);       // gathers for q=p+3
    MSTEP(p & 1, ((p >> 1) % 3), p & 1);
    if (p + 2 < 18) FIN(p & 1, (((p + 2) >> 1) % 3), p & 1);   // q=p+2
    if (p + 4 < 18) PARAMS(p + 4, p & 1);
    if (p < 17) {
      if (p <= 14) asm volatile("s_waitcnt vmcnt(32)" ::: "memory");  // drain A-glds, keep 32 gathers
      else         asm volatile("s_waitcnt vmcnt(0)"  ::: "memory");
      asm volatile("s_waitcnt lgkmcnt(0)" ::: "memory");              // ds_writes + param loads done
      __builtin_amdgcn_s_barrier();
      __builtin_amdgcn_sched_barrier(0);
    }
  }

  float* ob = out + (size_t)b * O_ * HW + pbase;
#pragma unroll
  for (int m = 0; m < 4; ++m) {
    int o0 = wr * 64 + m * 16 + lhi * 4;
#pragma unroll
    for (int n = 0; n < 2; ++n) {
      int px = wc * 32 + n * 16 + llo;
#pragma unroll
      for (int r = 0; r < 4; ++r)
        ob[(size_t)(o0 + r) * HW + px] = acc[m][n][r];
    }
  }
}

extern "C" void kernel_launch(void* const* d_in, const int* in_sizes, int n_in,
                              void* d_out, int out_size, void* d_ws, size_t ws_size,
                              hipStream_t stream) {
  const float* x      = (const float*)d_in[0];
  const float* w_off  = (const float*)d_in[1];
  const float* b_off  = (const float*)d_in[2];
  const float* w_msk  = (const float*)d_in[3];
  const float* b_msk  = (const float*)d_in[4];
  const float* weight = (const float*)d_in[5];
  float* out = (float*)d_out;
  char* ws = (char*)d_ws;

  unsigned short* Wbf  = (unsigned short*)(ws + WS_WBF);
  unsigned short* wcb  = (unsigned short*)(ws + WS_WCB);
  float*          zero = (float*)(ws + WS_ZERO);
  unsigned short* xt   = (unsigned short*)(ws + WS_XT);
  uint2*          pwh  = (uint2*)(ws + WS_PW);
  unsigned*       paw  = (unsigned*)(ws + WS_PA);
  float*          cgo  = (float*)(ws + WS_COUT);

  k_px    <<<1088, 256, 0, stream>>>(weight, w_off, w_msk, x, Wbf, wcb, zero, xt);
  k_cgemm <<<256, 256, 0, stream>>>(xt, wcb, zero, cgo);
  k_rp    <<<1152, 256, 0, stream>>>(cgo, b_off, b_msk, pwh, paw);
  k_fused <<<512, 256, 0, stream>>>((const unsigned*)xt, pwh, paw, Wbf, out);
}

// Round 12
// 127.961 us; speedup vs baseline: 2.6357x; 1.0303x over previous
//
#include <hip/hip_runtime.h>
#include <hip/hip_fp16.h>
#include <cstdint>

#define B_    8
#define C_    128
#define HW    4096      // 64*64
#define O_    128
#define KDIM  1152      // C_*9

typedef short bf16x8 __attribute__((ext_vector_type(8)));
typedef float f32x4  __attribute__((ext_vector_type(4)));

__device__ __forceinline__ unsigned short f2bf(float f) {
  unsigned u = __float_as_uint(f);
  u += 0x7FFFu + ((u >> 16) & 1u);
  return (unsigned short)(u >> 16);
}
__device__ __forceinline__ float bf_lo(unsigned u) { return __uint_as_float(u << 16); }
__device__ __forceinline__ float bf_hi(unsigned u) { return __uint_as_float(u & 0xFFFF0000u); }

// ---------------- workspace layout (bytes) ----------------
#define WS_WBF   0          // 128*1152*2           =   294,912
#define WS_WCB   294912     // 9*32*128*2           =    73,728
#define WS_ZERO  368640     // 256B zero row
#define WS_XT    368896     // 8*4096*128*2         = 8,388,608 -> 8,757,504
#define WS_PW    8757504    // 294912*8             = 2,359,296 -> 11,116,800
#define WS_PA    11116800   // 294912*4             = 1,179,648 -> 12,296,448
#define WS_COUT  12296448   // 8*4096*32*4          = 4,194,304 -> 16,490,752

// K0 merged: [bid<576] Wbf/wcb/zero prep ; [bid>=576] x -> xt transpose
__global__ __launch_bounds__(256) void k_px(const float* __restrict__ weight,
                                            const float* __restrict__ w_off,
                                            const float* __restrict__ w_msk,
                                            const float* __restrict__ x,
                                            unsigned short* __restrict__ Wbf,
                                            unsigned short* __restrict__ wcb,
                                            float* __restrict__ zero,
                                            unsigned short* __restrict__ xt) {
  __shared__ unsigned short tile[64][130];
  int bid = blockIdx.x;
  int tid = threadIdx.x;
  if (bid < 576) {
    int gid = bid * 256 + tid;
    if (gid < O_ * KDIM) {
      int o = gid / KDIM, i = gid - o * KDIM;
      int k2 = i >> 7, c = i & 127;
      Wbf[gid] = f2bf(weight[o * KDIM + c * 9 + k2]);
    }
    if (gid < 9 * 32 * 128) {
      int t = gid >> 12, rem = gid & 4095;
      int o = rem >> 7, c = rem & 127;
      float v = 0.f;
      if (o < 18) v = w_off[o * KDIM + c * 9 + t];
      else if (o < 27) v = w_msk[(o - 18) * KDIM + c * 9 + t];
      wcb[gid] = f2bf(v);
    }
    if (gid < 64) zero[gid] = 0.f;
    return;
  }
  int xb_id = bid - 576;                     // 512 = 8b * 64 ptiles
  int b = xb_id >> 6, p0 = (xb_id & 63) << 6;
  int pl = tid & 63, cq = tid >> 6;
  const float* xb = x + (size_t)b * C_ * HW + p0 + pl;
#pragma unroll
  for (int i = 0; i < 32; ++i) {
    int c = cq * 32 + i;
    tile[pl][c] = f2bf(xb[(size_t)c * HW]);
  }
  __syncthreads();
  int cd = tid & 63, pr = tid >> 6;
  unsigned* dst = (unsigned*)xt + ((size_t)b * HW + p0) * 64 + cd;
  const unsigned* t32 = (const unsigned*)&tile[0][0];
#pragma unroll
  for (int j = 0; j < 16; ++j) {
    int p = pr + j * 4;
    dst[(size_t)p * 64] = t32[p * 65 + cd];
  }
}

// K1: offset/mask conv as MFMA GEMM: cout[b][p][32]
// XCD swizzle: b = bid&7 so each batch's xt stays in one XCD's L2
__global__ __launch_bounds__(256) void k_cgemm(const unsigned short* __restrict__ xt,
                                               const unsigned short* __restrict__ wcb,
                                               const float* __restrict__ zero,
                                               float* __restrict__ cout) {
  __shared__ __align__(16) unsigned short As[2][128 * 128];
  __shared__ __align__(16) unsigned short Bs[2][32 * 128];

  int bid = blockIdx.x;            // 256 = 32 ptiles * 8 b (b minor -> XCD-local)
  int b = bid & 7;
  int p0 = (bid >> 3) << 7;
  int tid = threadIdx.x, lane = tid & 63, wv = tid >> 6;
  int lhi = lane >> 4, llo = lane & 15;

  const unsigned short* xb = xt + (size_t)b * HW * C_;

  auto STAGE = [&](int t, int bufi) {
    int ky = t / 3, kx = t - ky * 3;
    int dshift = (ky - 1) * 64 + (kx - 1);
#pragma unroll
    for (int i = 0; i < 8; ++i) {
      int chunk = i * 256 + tid;
      int r = chunk >> 4, j = chunk & 15;
      int p = p0 + r;
      int ho = p >> 6, wo = p & 63;
      int iy = ho + ky - 1, ix = wo + kx - 1;
      bool valid = ((unsigned)iy < 64u) && ((unsigned)ix < 64u);
      int jj = j ^ (r & 15);
      const unsigned short* src = valid ? (xb + (size_t)(p + dshift) * C_ + jj * 8)
                                        : (const unsigned short*)zero;
      __builtin_amdgcn_global_load_lds(
          (const __attribute__((address_space(1))) unsigned*)src,
          (__attribute__((address_space(3))) unsigned*)((char*)&As[bufi][0] + i * 4096 + wv * 1024),
          16, 0, 0);
    }
#pragma unroll
    for (int i = 0; i < 2; ++i) {
      int chunk = i * 256 + tid;
      int o = chunk >> 4, j = chunk & 15;
      int jj = j ^ (o & 15);
      __builtin_amdgcn_global_load_lds(
          (const __attribute__((address_space(1))) unsigned*)(wcb + (size_t)t * 4096 + o * 128 + jj * 8),
          (__attribute__((address_space(3))) unsigned*)((char*)&Bs[bufi][0] + i * 4096 + wv * 1024),
          16, 0, 0);
    }
  };

  f32x4 acc[2][2] = {};
  STAGE(0, 0);
  __syncthreads();
  int buf = 0;
  for (int t = 0; t < 9; ++t) {
    if (t < 8) STAGE(t + 1, buf ^ 1);
    bf16x8 bfv[2][4];
#pragma unroll
    for (int n = 0; n < 2; ++n)
#pragma unroll
      for (int ks = 0; ks < 4; ++ks) {
        int row = n * 16 + llo;
        int off = row * 256 + (((ks * 4 + lhi) ^ (row & 15)) << 4);
        bfv[n][ks] = *(const bf16x8*)((const char*)&Bs[buf][0] + off);
      }
#pragma unroll
    for (int ks = 0; ks < 4; ++ks) {
      bf16x8 af[2];
#pragma unroll
      for (int m = 0; m < 2; ++m) {
        int row = wv * 32 + m * 16 + llo;
        int off = row * 256 + (((ks * 4 + lhi) ^ (row & 15)) << 4);
        af[m] = *(const bf16x8*)((const char*)&As[buf][0] + off);
      }
#pragma unroll
      for (int m = 0; m < 2; ++m)
#pragma unroll
        for (int n = 0; n < 2; ++n)
          acc[m][n] = __builtin_amdgcn_mfma_f32_16x16x32_bf16(af[m], bfv[n][ks], acc[m][n], 0, 0, 0);
    }
    __syncthreads();
    buf ^= 1;
  }

  float* cb = cout + ((size_t)b * HW + p0) * 32;
#pragma unroll
  for (int m = 0; m < 2; ++m)
#pragma unroll
    for (int n = 0; n < 2; ++n)
#pragma unroll
      for (int r = 0; r < 4; ++r) {
        int pix = wv * 32 + m * 16 + lhi * 4 + r;
        int o = n * 16 + llo;
        cb[(size_t)pix * 32 + o] = acc[m][n][r];
      }
}

// K1b: bias + sigmoid + bilinear params, one thread per (b,k2,p)
__global__ __launch_bounds__(256) void k_rp(const float* __restrict__ cout,
                                            const float* __restrict__ b_off,
                                            const float* __restrict__ b_msk,
                                            uint2* __restrict__ pwh,
                                            unsigned* __restrict__ paw) {
  int gid = blockIdx.x * 256 + threadIdx.x;   // < 294912, = (b*9+k2)*4096 + p
  int p = gid & 4095;
  int bk = gid >> 12;                          // block-uniform
  int b = bk / 9, k2 = bk - 9 * b;
  const float* cr = cout + ((size_t)b * HW + p) * 32;
  float dy = cr[2 * k2]     + b_off[2 * k2];
  float dx = cr[2 * k2 + 1] + b_off[2 * k2 + 1];
  float mk = cr[18 + k2]    + b_msk[k2];
  mk = 1.f / (1.f + __expf(-mk));
  int ho = p >> 6, wo = p & 63;
  int ky = k2 / 3, kx = k2 - ky * 3;
  float py = dy + (float)(ho + ky - 1);
  float px = dx + (float)(wo + kx - 1);
  float fy = floorf(py), fx = floorf(px);
  float ly = py - fy, lx = px - fx;
  int y0 = (int)fy, x0 = (int)fx;
  float vy0 = ((unsigned)y0 < 64u) ? 1.f : 0.f;
  float vy1 = ((unsigned)(y0 + 1) < 64u) ? 1.f : 0.f;
  float vx0 = ((unsigned)x0 < 64u) ? 1.f : 0.f;
  float vx1 = ((unsigned)(x0 + 1) < 64u) ? 1.f : 0.f;
  int cy0 = min(max(y0, 0), 63);
  int cx0 = min(max(x0, 0), 63);
  float wy0 = (1.f - ly) * mk, wy1 = ly * mk;
  float w00 = wy0 * (1.f - lx) * vy0 * vx0, w01 = wy0 * lx * vy0 * vx1;
  float w10 = wy1 * (1.f - lx) * vy1 * vx0, w11 = wy1 * lx * vy1 * vx1;
  int dxf = (x0 >= 0 && x0 <= 62) ? 1 : 0;
  int dyf = (y0 >= 0 && y0 <= 62) ? 1 : 0;
  unsigned h00 = __half_as_ushort(__float2half_rn(w00));
  unsigned h01 = __half_as_ushort(__float2half_rn(w01));
  unsigned h10 = __half_as_ushort(__float2half_rn(w10));
  unsigned h11 = __half_as_ushort(__float2half_rn(w11));
  pwh[gid] = make_uint2(h00 | (h01 << 16), h10 | (h11 << 16));
  paw[gid] = (unsigned)(cy0 * 64 + cx0) | (dxf << 12) | (dyf << 13);
}

// K2: fused sample+GEMM, 18 half-tap phases, 3 B-buffers, raw barriers + counted waits.
// XCD swizzle: b = bid&7 -> all gathers for batch b stay in XCD b's L2.
__global__ __launch_bounds__(256, 2) void k_fused(const unsigned* __restrict__ xt32,
                                                  const uint2* __restrict__ pwh,
                                                  const unsigned* __restrict__ paw,
                                                  const unsigned short* __restrict__ Wbf,
                                                  float* __restrict__ out) {
  __shared__ __align__(16) unsigned short As[2][128 * 64];   // 16KB x2: Wbf K-step tiles
  __shared__ __align__(16) unsigned short Bs[3][64 * 128];   // 16KB x3: val tap tiles

  int bid = blockIdx.x;            // 512 = 64 ptiles * 8 b (b minor -> XCD-local)
  int b = bid & 7;
  int pbase = (bid >> 3) << 6;
  int tid = threadIdx.x, lane = tid & 63;
  int wuni = __builtin_amdgcn_readfirstlane(tid >> 6);
  int wr = wuni >> 1, wc = wuni & 1;
  int lhi = lane >> 4, llo = lane & 15;

  const unsigned* xb32 = xt32 + ((size_t)b << 18);

  // param sets (wave-uniform) and gather sets, all const-indexed
  uint2 Wv[2][8]; unsigned Av[2][8]; unsigned g[2][32];

  auto PARAMS = [&](int q, int s) {         // load params for half-tap q into set s
    int tap = q >> 1, half = q & 1;
    int base = (b * 9 + tap) * HW + pbase + wuni * 16 + half * 8;   // uniform
#pragma unroll
    for (int i = 0; i < 8; ++i) { Wv[s][i] = pwh[base + i]; Av[s][i] = paw[base + i]; }
  };
  auto ISSUE = [&](int s) {                 // 32 gathers from set s params
#pragma unroll
    for (int i = 0; i < 8; ++i) {
      unsigned aw = Av[s][i];
      unsigned a00 = (aw & 4095u) << 6;
      unsigned dxs = ((aw >> 12) & 1u) << 6;
      unsigned dys = ((aw >> 13) & 1u) << 12;
      g[s][i * 4 + 0] = xb32[a00 + lane];
      g[s][i * 4 + 1] = xb32[a00 + dxs + lane];
      g[s][i * 4 + 2] = xb32[a00 + dys + lane];
      g[s][i * 4 + 3] = xb32[a00 + dys + dxs + lane];
    }
  };
  auto FIN = [&](int s, int bufn, int half) {  // blend + swizzled ds_write (8 rows)
#pragma unroll
    for (int i = 0; i < 8; ++i) {
      float2 f0 = __half22float2(*reinterpret_cast<__half2*>(&Wv[s][i].x));
      float2 f1 = __half22float2(*reinterpret_cast<__half2*>(&Wv[s][i].y));
      unsigned v00 = g[s][i*4], v01 = g[s][i*4+1], v10 = g[s][i*4+2], v11 = g[s][i*4+3];
      float lo = f0.x*bf_lo(v00) + f0.y*bf_lo(v01) + f1.x*bf_lo(v10) + f1.y*bf_lo(v11);
      float hi = f0.x*bf_hi(v00) + f0.y*bf_hi(v01) + f1.x*bf_hi(v10) + f1.y*bf_hi(v11);
      unsigned pk = (unsigned)f2bf(lo) | ((unsigned)f2bf(hi) << 16);
      int row = wuni * 16 + half * 8 + i;
      unsigned off = (unsigned)(row * 256) + (((unsigned)lane * 4u) ^ ((unsigned)(row & 7) << 4));
      *(unsigned*)((char*)&Bs[bufn][0] + off) = pk;
    }
  };
  auto STAGE_A = [&](int kt, int abuf) {    // Wbf K-step via glds + swizzle
#pragma unroll
    for (int j = 0; j < 4; ++j) {
      int chunk = j * 256 + tid;
      int row = chunk >> 3;
      int sch = (chunk & 7) ^ (row & 7);
      __builtin_amdgcn_global_load_lds(
          (const __attribute__((address_space(1))) unsigned*)(Wbf + (size_t)row * KDIM + kt * 64 + sch * 8),
          (__attribute__((address_space(3))) unsigned*)((char*)&As[abuf][0] + j * 4096 + wuni * 1024),
          16, 0, 0);
    }
  };

  f32x4 acc[4][2] = {};
  auto MSTEP = [&](int abuf, int bbuf, int kh) {
    __builtin_amdgcn_s_setprio(1);
#pragma unroll
    for (int ks = 0; ks < 2; ++ks) {
      bf16x8 af[4], bfv[2];
#pragma unroll
      for (int m = 0; m < 4; ++m) {
        int row = wr * 64 + m * 16 + llo;
        int off = row * 128 + ((ks * 64 + lhi * 16) ^ ((llo & 7) << 4));
        af[m] = *(const bf16x8*)((const char*)&As[abuf][0] + off);
      }
#pragma unroll
      for (int n = 0; n < 2; ++n) {
        int row = wc * 32 + n * 16 + llo;
        int off = row * 256 + ((kh * 128 + ks * 64 + lhi * 16) ^ ((row & 7) << 4));
        bfv[n] = *(const bf16x8*)((const char*)&Bs[bbuf][0] + off);
      }
#pragma unroll
      for (int m = 0; m < 4; ++m)
#pragma unroll
        for (int n = 0; n < 2; ++n)
          acc[m][n] = __builtin_amdgcn_mfma_f32_16x16x32_bf16(af[m], bfv[n], acc[m][n], 0, 0, 0);
    }
    __builtin_amdgcn_s_setprio(0);
  };

  // prologue: q=0,1 built into Bs[0]; q=2 params+gathers in flight; A k-step 0 staged
  PARAMS(0, 0); PARAMS(1, 1);
  ISSUE(0); ISSUE(1);
  FIN(0, 0, 0);                 // q=0 -> Bs[0] half0 (frees g[0])
  PARAMS(2, 0);                 // q=2 params -> set 0
  FIN(1, 0, 1);                 // q=1 -> Bs[0] half1
  PARAMS(3, 1);                 // q=3 params -> set 1
  ISSUE(0);                     // q=2 gathers -> g[0]
  STAGE_A(0, 0);
  __syncthreads();              // one-time full drain

  // phases p=0..17
#pragma unroll 6
  for (int p = 0; p < 18; ++p) {
    if (p + 1 < 18) STAGE_A(p + 1, (p + 1) & 1);
    __builtin_amdgcn_sched_barrier(0);        // keep A-glds oldest in vmcnt order
    if (p + 3 < 18) ISSUE((p + 1) & 1);       // gathers for q=p+3
    MSTEP(p & 1, ((p >> 1) % 3), p & 1);
    if (p + 2 < 18) FIN(p & 1, (((p + 2) >> 1) % 3), p & 1);   // q=p+2
    if (p + 4 < 18) PARAMS(p + 4, p & 1);
    if (p < 17) {
      if (p <= 14) asm volatile("s_waitcnt vmcnt(32)" ::: "memory");  // drain A-glds, keep 32 gathers
      else         asm volatile("s_waitcnt vmcnt(0)"  ::: "memory");
      asm volatile("s_waitcnt lgkmcnt(0)" ::: "memory");              // ds_writes + param loads done
      __builtin_amdgcn_s_barrier();
      __builtin_amdgcn_sched_barrier(0);
    }
  }

  float* ob = out + (size_t)b * O_ * HW + pbase;
#pragma unroll
  for (int m = 0; m < 4; ++m) {
    int o0 = wr * 64 + m * 16 + lhi * 4;
#pragma unroll
    for (int n = 0; n < 2; ++n) {
      int px = wc * 32 + n * 16 + llo;
#pragma unroll
      for (int r = 0; r < 4; ++r)
        ob[(size_t)(o0 + r) * HW + px] = acc[m][n][r];
    }
  }
}

extern "C" void kernel_launch(void* const* d_in, const int* in_sizes, int n_in,
                              void* d_out, int out_size, void* d_ws, size_t ws_size,
                              hipStream_t stream) {
  const float* x      = (const float*)d_in[0];
  const float* w_off  = (const float*)d_in[1];
  const float* b_off  = (const float*)d_in[2];
  const float* w_msk  = (const float*)d_in[3];
  const float* b_msk  = (const float*)d_in[4];
  const float* weight = (const float*)d_in[5];
  float* out = (float*)d_out;
  char* ws = (char*)d_ws;

  unsigned short* Wbf  = (unsigned short*)(ws + WS_WBF);
  unsigned short* wcb  = (unsigned short*)(ws + WS_WCB);
  float*          zero = (float*)(ws + WS_ZERO);
  unsigned short* xt   = (unsigned short*)(ws + WS_XT);
  uint2*          pwh  = (uint2*)(ws + WS_PW);
  unsigned*       paw  = (unsigned*)(ws + WS_PA);
  float*          cgo  = (float*)(ws + WS_COUT);

  k_px    <<<1088, 256, 0, stream>>>(weight, w_off, w_msk, x, Wbf, wcb, zero, xt);
  k_cgemm <<<256, 256, 0, stream>>>(xt, wcb, zero, cgo);
  k_rp    <<<1152, 256, 0, stream>>>(cgo, b_off, b_msk, pwh, paw);
  k_fused <<<512, 256, 0, stream>>>((const unsigned*)xt, pwh, paw, Wbf, out);
}